// Round 22
// baseline (195.833 us; speedup 1.0000x reference)
//
#include <hip/hip_runtime.h>
#include <hip/hip_bf16.h>
#include <stdint.h>

// ---------- common ----------
typedef __attribute__((ext_vector_type(8))) short bf16x8;
typedef __attribute__((ext_vector_type(4))) float f32x4;

__device__ __forceinline__ ushort f2bf(float f) {
    union { float f; uint32_t u; } c; c.f = f;
    uint32_t u = c.u;
    uint32_t r = (u + 0x7FFFu + ((u >> 16) & 1u)) >> 16;
    return (ushort)r;
}

__device__ __forceinline__ void load16_to_lds(const void* gsrc, void* ldst) {
    __builtin_amdgcn_global_load_lds(
        (const __attribute__((address_space(1))) uint32_t*)gsrc,
        (__attribute__((address_space(3))) uint32_t*)ldst,
        16, 0, 0);
}

// ---------- f32 -> bf16 convert (fallback path only) ----------
__global__ __launch_bounds__(256) void f32_to_bf16_kernel(
    const float* __restrict__ in, ushort* __restrict__ out, int n)
{
    int i = (blockIdx.x * 256 + threadIdx.x) * 8;
    if (i >= n) return;
    float4 a = *(const float4*)(in + i);
    float4 b = *(const float4*)(in + i + 4);
    ushort4 o0, o1;
    o0.x = f2bf(a.x); o0.y = f2bf(a.y); o0.z = f2bf(a.z); o0.w = f2bf(a.w);
    o1.x = f2bf(b.x); o1.y = f2bf(b.y); o1.z = f2bf(b.z); o1.w = f2bf(b.w);
    *(ushort4*)(out + i) = o0;
    *(ushort4*)(out + i + 4) = o1;
}

// ---------- feature transpose: [2,256,32,32] -> [2,32,32,256] ----------
__global__ __launch_bounds__(256) void transpose_feat_kernel(
    const float* __restrict__ feat, float* __restrict__ featT)
{
    int bc = blockIdx.x;
    int b = bc >> 8;
    int c = bc & 255;
    const float* src = feat + (size_t)bc * 1024;
    float* dst = featT + (size_t)b * 262144 + c;
    #pragma unroll
    for (int i = 0; i < 4; ++i) {
        int p = i * 256 + threadIdx.x;
        dst[(size_t)p * 256] = src[p];
    }
}

// ---------- fused ROI align (separable) + weight converts ----------
__global__ __launch_bounds__(512) void roi_conv_kernel(
    const float* __restrict__ featT, const float* __restrict__ props,
    ushort* __restrict__ pooled,
    const float* __restrict__ w1, ushort* __restrict__ w1b,
    const float* __restrict__ w2, ushort* __restrict__ w2b)
{
    __shared__ int   si0[28];
    __shared__ int   si1[28];
    __shared__ float sl[28];
    __shared__ float sv[28];
    __shared__ float Aw[7][10];
    __shared__ float Bw[7][10];
    __shared__ __align__(16) ushort outbuf[12544];
    const int tid = threadIdx.x;
    const int blk = blockIdx.x;

    if (blk >= 2048) {
        const float* src;
        ushort* dst;
        int base;
        if (blk < 2048 + 1568) { src = w1; dst = w1b; base = (blk - 2048) * 8192; }
        else                   { src = w2; dst = w2b; base = (blk - 3616) * 8192; }
        int i = base + tid * 16;
        #pragma unroll
        for (int h = 0; h < 2; ++h) {
            float4 a = *(const float4*)(src + i + h * 8);
            float4 b = *(const float4*)(src + i + h * 8 + 4);
            ushort4 o0, o1;
            o0.x = f2bf(a.x); o0.y = f2bf(a.y); o0.z = f2bf(a.z); o0.w = f2bf(a.w);
            o1.x = f2bf(b.x); o1.y = f2bf(b.y); o1.z = f2bf(b.z); o1.w = f2bf(b.w);
            *(ushort4*)(dst + i + h * 8) = o0;
            *(ushort4*)(dst + i + h * 8 + 4) = o1;
        }
        return;
    }

    const int roi = blk;
    const int b = roi >> 10;
    if (tid < 28) {
        int axis = (tid >= 14) ? 1 : 0;
        int pp = tid - axis * 14;
        float c0 = props[roi * 4 + (axis ? 0 : 1)] * (1.f / 32.f);
        float c1 = props[roi * 4 + (axis ? 2 : 3)] * (1.f / 32.f);
        float sz = fmaxf(c1 - c0, 1.f);
        float bsz = sz * (1.f / 7.f);
        float g = (float)(pp >> 1) + ((float)(pp & 1) + 0.5f) * 0.5f;
        float c = c0 + g * bsz;
        float valid = (c > -1.f && c < 32.f) ? 1.f : 0.f;
        float cc = fminf(fmaxf(c, 0.f), 31.f);
        float fl = floorf(cc);
        int i0 = (int)fl;
        si0[tid] = i0;
        si1[tid] = min(i0 + 1, 31);
        sl[tid] = cc - fl;
        sv[tid] = valid;
    }
    __syncthreads();

    const int r0 = si0[0];
    const int c0 = si0[14];

    if (tid < 140) {
        int axis = tid / 70;
        int e = tid - axis * 70;
        int oy = e / 10, yy = e - oy * 10;
        int base = axis * 14;
        int org = axis ? c0 : r0;
        float wsum = 0.f;
        #pragma unroll
        for (int s = 0; s < 2; ++s) {
            int p = base + oy * 2 + s;
            float w = 0.f;
            if (si0[p] - org == yy) w += 1.f - sl[p];
            if (si1[p] - org == yy) w += sl[p];
            wsum += sv[p] * w;
        }
        wsum *= 0.5f;
        if (axis == 0) Aw[oy][yy] = wsum;
        else           Bw[oy][yy] = wsum;
    }
    __syncthreads();

    const int grp = tid >> 8;
    const int ch = tid & 255;
    const float* fbase = featT + (size_t)b * 262144 + ch;

    int xoff[10];
    #pragma unroll
    for (int x = 0; x < 10; ++x) xoff[x] = min(c0 + x, 31) * 256;

    if (grp == 0) {
        float t[4][10];
        #pragma unroll
        for (int oy = 0; oy < 4; ++oy)
            #pragma unroll
            for (int x = 0; x < 10; ++x) t[oy][x] = 0.f;
        #pragma unroll
        for (int y = 0; y < 10; ++y) {
            const float* frow = fbase + (size_t)min(r0 + y, 31) * 8192;
            float a0 = Aw[0][y], a1 = Aw[1][y], a2 = Aw[2][y], a3 = Aw[3][y];
            #pragma unroll
            for (int x = 0; x < 10; ++x) {
                float fv = frow[xoff[x]];
                t[0][x] += a0 * fv;
                t[1][x] += a1 * fv;
                t[2][x] += a2 * fv;
                t[3][x] += a3 * fv;
            }
        }
        #pragma unroll
        for (int oy = 0; oy < 4; ++oy)
            #pragma unroll
            for (int ox = 0; ox < 7; ++ox) {
                float o = 0.f;
                #pragma unroll
                for (int x = 0; x < 10; ++x) o += Bw[ox][x] * t[oy][x];
                outbuf[ch * 49 + oy * 7 + ox] = f2bf(o);
            }
    } else {
        float t[3][10];
        #pragma unroll
        for (int oy = 0; oy < 3; ++oy)
            #pragma unroll
            for (int x = 0; x < 10; ++x) t[oy][x] = 0.f;
        #pragma unroll
        for (int y = 0; y < 10; ++y) {
            const float* frow = fbase + (size_t)min(r0 + y, 31) * 8192;
            float a4 = Aw[4][y], a5 = Aw[5][y], a6 = Aw[6][y];
            #pragma unroll
            for (int x = 0; x < 10; ++x) {
                float fv = frow[xoff[x]];
                t[0][x] += a4 * fv;
                t[1][x] += a5 * fv;
                t[2][x] += a6 * fv;
            }
        }
        #pragma unroll
        for (int oy = 0; oy < 3; ++oy)
            #pragma unroll
            for (int ox = 0; ox < 7; ++ox) {
                float o = 0.f;
                #pragma unroll
                for (int x = 0; x < 10; ++x) o += Bw[ox][x] * t[oy][x];
                outbuf[ch * 49 + (4 + oy) * 7 + ox] = f2bf(o);
            }
    }
    __syncthreads();

    const uint4* src = (const uint4*)outbuf;
    uint4* dst = (uint4*)(pooled + (size_t)roi * 12544);
    #pragma unroll
    for (int i = 0; i < 4; ++i) {
        int idx = i * 512 + tid;
        if (idx < 1568) dst[idx] = src[idx];
    }
}

// ---------- split-K GEMM, BK=32, double-buffered 2-phase (R12-proven) ----------
__global__ __launch_bounds__(256) void gemm_bt_split(
    const ushort* __restrict__ A, const ushort* __restrict__ Bm,
    float* __restrict__ part, int M, int N, int K, int klen)
{
    constexpr int BK = 32;
    __shared__ __align__(16) ushort lA[2][128][BK];
    __shared__ __align__(16) ushort lB[2][128][BK];
    const int tid = threadIdx.x;

    const int nbx = gridDim.x, nby = gridDim.y;
    const int nwg = nbx * nby * gridDim.z;
    const int d = blockIdx.x + nbx * (blockIdx.y + nby * blockIdx.z);
    const int t = (d & 7) * (nwg >> 3) + (d >> 3);
    const int n_blk = t % nbx;
    const int m_blk = (t / nbx) % nby;
    const int k_blk = t / (nbx * nby);

    const int m0 = m_blk * 128;
    const int n0 = n_blk * 128;
    const int k_start = k_blk * klen;

    const int w = tid >> 6, l = tid & 63;
    const int wr = w >> 1, wcid = w & 1;
    const int lrow = l & 15;
    const int lkb = (((l >> 4) ^ ((lrow >> 1) & 3)) * 16);

    const int sc0 = tid, sc1 = 256 + tid;
    const int srow0 = sc0 >> 2, srow1 = sc1 >> 2;
    const int scol0 = ((sc0 & 3) ^ ((srow0 >> 1) & 3)) * 16;
    const int scol1 = ((sc1 & 3) ^ ((srow1 >> 1) & 3)) * 16;

    const int nsteps = klen / BK;

    {
        int k0 = k_start;
        load16_to_lds((const char*)(A + (size_t)(m0 + srow0) * K + k0) + scol0, ((char*)lA[0]) + sc0 * 16);
        load16_to_lds((const char*)(A + (size_t)(m0 + srow1) * K + k0) + scol1, ((char*)lA[0]) + sc1 * 16);
        load16_to_lds((const char*)(Bm + (size_t)(n0 + srow0) * K + k0) + scol0, ((char*)lB[0]) + sc0 * 16);
        load16_to_lds((const char*)(Bm + (size_t)(n0 + srow1) * K + k0) + scol1, ((char*)lB[0]) + sc1 * 16);
    }
    __syncthreads();

    f32x4 acc[4][4] = {};
    int cur = 0;

    for (int ts = 0; ts < nsteps; ++ts) {
        if (ts + 1 < nsteps) {
            int k0 = k_start + (ts + 1) * BK;
            int nxt = cur ^ 1;
            load16_to_lds((const char*)(A + (size_t)(m0 + srow0) * K + k0) + scol0, ((char*)lA[nxt]) + sc0 * 16);
            load16_to_lds((const char*)(A + (size_t)(m0 + srow1) * K + k0) + scol1, ((char*)lA[nxt]) + sc1 * 16);
            load16_to_lds((const char*)(Bm + (size_t)(n0 + srow0) * K + k0) + scol0, ((char*)lB[nxt]) + sc0 * 16);
            load16_to_lds((const char*)(Bm + (size_t)(n0 + srow1) * K + k0) + scol1, ((char*)lB[nxt]) + sc1 * 16);
        }

        bf16x8 af[4], bfr[4];
        #pragma unroll
        for (int m = 0; m < 4; ++m)
            af[m] = *(const bf16x8*)(((const char*)lA[cur]) + (wr * 64 + m * 16 + lrow) * 64 + lkb);
        #pragma unroll
        for (int n = 0; n < 4; ++n)
            bfr[n] = *(const bf16x8*)(((const char*)lB[cur]) + (wcid * 64 + n * 16 + lrow) * 64 + lkb);
        #pragma unroll
        for (int m = 0; m < 4; ++m)
            #pragma unroll
            for (int n = 0; n < 4; ++n)
                acc[m][n] = __builtin_amdgcn_mfma_f32_16x16x32_bf16(af[m], bfr[n], acc[m][n], 0, 0, 0);

        __syncthreads();
        cur ^= 1;
    }

    const int r4 = (l >> 4) * 4;
    const int cc = l & 15;
    float* pb = part + (size_t)k_blk * M * N;
    #pragma unroll
    for (int m = 0; m < 4; ++m) {
        #pragma unroll
        for (int n = 0; n < 4; ++n) {
            int col = n0 + wcid * 64 + n * 16 + cc;
            #pragma unroll
            for (int j = 0; j < 4; ++j) {
                int row = m0 + wr * 64 + m * 16 + r4 + j;
                pb[(size_t)row * N + col] = acc[m][n][j];
            }
        }
    }
}

// ---------- reduce split-K partials + bias + relu + bf16 cast (x1) ----------
template<bool OUT_BF16>
__global__ __launch_bounds__(256) void reduce_split_kernel(
    const float* __restrict__ part, const float* __restrict__ bias,
    void* __restrict__ out, int MN, int N, int S, int relu)
{
    int i4 = (blockIdx.x * 256 + threadIdx.x) * 4;
    if (i4 >= MN) return;
    float4 a = *(const float4*)(part + i4);
    for (int s = 1; s < S; ++s) {
        float4 b = *(const float4*)(part + (size_t)s * MN + i4);
        a.x += b.x; a.y += b.y; a.z += b.z; a.w += b.w;
    }
    int bc = i4 & (N - 1);
    float4 bv = *(const float4*)(bias + bc);
    a.x += bv.x; a.y += bv.y; a.z += bv.z; a.w += bv.w;
    if (relu) {
        a.x = fmaxf(a.x, 0.f); a.y = fmaxf(a.y, 0.f);
        a.z = fmaxf(a.z, 0.f); a.w = fmaxf(a.w, 0.f);
    }
    if (OUT_BF16) {
        ushort4 o; o.x = f2bf(a.x); o.y = f2bf(a.y); o.z = f2bf(a.z); o.w = f2bf(a.w);
        *(ushort4*)((ushort*)out + i4) = o;
    } else {
        *(float4*)((float*)out + i4) = a;
    }
}

// ---------- fused tail: reduce2 + bias + relu + heads + decode + softmax ----------
__global__ __launch_bounds__(256) void fused_tail_kernel(
    const float* __restrict__ part, const float* __restrict__ b2,
    const float* __restrict__ wc, const float* __restrict__ bc,
    const float* __restrict__ wb, const float* __restrict__ bb,
    const float* __restrict__ props, float* __restrict__ out, int S)
{
    const int row = blockIdx.x;
    const int tid = threadIdx.x;
    const int i4 = tid * 4;
    const size_t MN = 2048 * 1024;
    const float* pr = part + (size_t)row * 1024 + i4;

    float4 a = *(const float4*)pr;
    for (int s = 1; s < S; ++s) {
        float4 b = *(const float4*)(pr + (size_t)s * MN);
        a.x += b.x; a.y += b.y; a.z += b.z; a.w += b.w;
    }
    float4 bv = *(const float4*)(b2 + i4);
    a.x = fmaxf(a.x + bv.x, 0.f);
    a.y = fmaxf(a.y + bv.y, 0.f);
    a.z = fmaxf(a.z + bv.z, 0.f);
    a.w = fmaxf(a.w + bv.w, 0.f);

    float acc[10];
    #pragma unroll
    for (int o = 0; o < 10; ++o) {
        const float* wrow = (o < 2) ? (wc + o * 1024) : (wb + (o - 2) * 1024);
        float4 wv = *(const float4*)(wrow + i4);
        acc[o] = a.x * wv.x + a.y * wv.y + a.z * wv.z + a.w * wv.w;
    }
    #pragma unroll
    for (int o = 0; o < 10; ++o) {
        float v = acc[o];
        #pragma unroll
        for (int s = 32; s > 0; s >>= 1) v += __shfl_xor(v, s, 64);
        acc[o] = v;
    }

    __shared__ float red[10][4];
    const int wv = tid >> 6, ln = tid & 63;
    if (ln == 0) {
        #pragma unroll
        for (int o = 0; o < 10; ++o) red[o][wv] = acc[o];
    }
    __syncthreads();

    if (tid == 0) {
        float h[10];
        #pragma unroll
        for (int o = 0; o < 10; ++o)
            h[o] = red[o][0] + red[o][1] + red[o][2] + red[o][3];
        float cls0 = h[0] + bc[0];
        float cls1 = h[1] + bc[1];
        float bx[8];
        #pragma unroll
        for (int o = 0; o < 8; ++o) bx[o] = h[2 + o] + bb[o];

        out[row * 2 + 0] = cls0;
        out[row * 2 + 1] = cls1;
        #pragma unroll
        for (int o = 0; o < 8; ++o) out[4096 + row * 8 + o] = bx[o];

        float px1 = props[row * 4 + 0], py1 = props[row * 4 + 1];
        float px2 = props[row * 4 + 2], py2 = props[row * 4 + 3];
        float pw = px2 - px1, ph = py2 - py1;
        float cx = px1 + 0.5f * pw, cy = py1 + 0.5f * ph;
        const float CLIP = 4.135166556742356f;
        float* boxes = out + 20480;
        #pragma unroll
        for (int k = 0; k < 2; ++k) {
            float dx = bx[k * 4 + 0] * 0.1f;
            float dy = bx[k * 4 + 1] * 0.1f;
            float dw = fminf(bx[k * 4 + 2] * 0.2f, CLIP);
            float dh = fminf(bx[k * 4 + 3] * 0.2f, CLIP);
            float pcx = dx * pw + cx, pcy = dy * ph + cy;
            float ppw = expf(dw) * pw, pph = expf(dh) * ph;
            boxes[row * 8 + k * 4 + 0] = fminf(fmaxf(pcx - 0.5f * ppw, 0.f), 1024.f);
            boxes[row * 8 + k * 4 + 1] = fminf(fmaxf(pcy - 0.5f * pph, 0.f), 1024.f);
            boxes[row * 8 + k * 4 + 2] = fminf(fmaxf(pcx + 0.5f * ppw, 0.f), 1024.f);
            boxes[row * 8 + k * 4 + 3] = fminf(fmaxf(pcy + 0.5f * pph, 0.f), 1024.f);
        }
        float m = fmaxf(cls0, cls1);
        float e0 = expf(cls0 - m), e1 = expf(cls1 - m);
        float inv = 1.f / (e0 + e1);
        out[36864 + row * 2 + 0] = e0 * inv;
        out[36864 + row * 2 + 1] = e1 * inv;
    }
}

// ---------- fallback kernels (ws too small path) ----------
__global__ __launch_bounds__(512) void roi_align_kernel(
    const float* __restrict__ featT, const float* __restrict__ props,
    ushort* __restrict__ pooled)
{
    int roi = blockIdx.x;
    int b = roi >> 10;
    __shared__ int   si0[28];
    __shared__ int   si1[28];
    __shared__ float sl[28];
    __shared__ float sv[28];
    __shared__ float Aw[7][10];
    __shared__ float Bw[7][10];
    __shared__ __align__(16) ushort outbuf[12544];
    int tid = threadIdx.x;
    if (tid < 28) {
        int axis = (tid >= 14) ? 1 : 0;
        int pp = tid - axis * 14;
        float c0 = props[roi * 4 + (axis ? 0 : 1)] * (1.f / 32.f);
        float c1 = props[roi * 4 + (axis ? 2 : 3)] * (1.f / 32.f);
        float sz = fmaxf(c1 - c0, 1.f);
        float bsz = sz * (1.f / 7.f);
        float g = (float)(pp >> 1) + ((float)(pp & 1) + 0.5f) * 0.5f;
        float c = c0 + g * bsz;
        float valid = (c > -1.f && c < 32.f) ? 1.f : 0.f;
        float cc = fminf(fmaxf(c, 0.f), 31.f);
        float fl = floorf(cc);
        int i0 = (int)fl;
        si0[tid] = i0;
        si1[tid] = min(i0 + 1, 31);
        sl[tid] = cc - fl;
        sv[tid] = valid;
    }
    __syncthreads();
    const int r0 = si0[0];
    const int c0 = si0[14];
    if (tid < 140) {
        int axis = tid / 70;
        int e = tid - axis * 70;
        int oy = e / 10, yy = e - oy * 10;
        int base = axis * 14;
        int org = axis ? c0 : r0;
        float wsum = 0.f;
        #pragma unroll
        for (int s = 0; s < 2; ++s) {
            int p = base + oy * 2 + s;
            float w = 0.f;
            if (si0[p] - org == yy) w += 1.f - sl[p];
            if (si1[p] - org == yy) w += sl[p];
            wsum += sv[p] * w;
        }
        wsum *= 0.5f;
        if (axis == 0) Aw[oy][yy] = wsum;
        else           Bw[oy][yy] = wsum;
    }
    __syncthreads();
    const int grp = tid >> 8;
    const int ch = tid & 255;
    const float* fbase = featT + (size_t)b * 262144 + ch;
    int xoff[10];
    #pragma unroll
    for (int x = 0; x < 10; ++x) xoff[x] = min(c0 + x, 31) * 256;
    if (grp == 0) {
        float t[4][10];
        #pragma unroll
        for (int oy = 0; oy < 4; ++oy)
            #pragma unroll
            for (int x = 0; x < 10; ++x) t[oy][x] = 0.f;
        #pragma unroll
        for (int y = 0; y < 10; ++y) {
            const float* frow = fbase + (size_t)min(r0 + y, 31) * 8192;
            float a0 = Aw[0][y], a1 = Aw[1][y], a2 = Aw[2][y], a3 = Aw[3][y];
            #pragma unroll
            for (int x = 0; x < 10; ++x) {
                float fv = frow[xoff[x]];
                t[0][x] += a0 * fv;
                t[1][x] += a1 * fv;
                t[2][x] += a2 * fv;
                t[3][x] += a3 * fv;
            }
        }
        #pragma unroll
        for (int oy = 0; oy < 4; ++oy)
            #pragma unroll
            for (int ox = 0; ox < 7; ++ox) {
                float o = 0.f;
                #pragma unroll
                for (int x = 0; x < 10; ++x) o += Bw[ox][x] * t[oy][x];
                outbuf[ch * 49 + oy * 7 + ox] = f2bf(o);
            }
    } else {
        float t[3][10];
        #pragma unroll
        for (int oy = 0; oy < 3; ++oy)
            #pragma unroll
            for (int x = 0; x < 10; ++x) t[oy][x] = 0.f;
        #pragma unroll
        for (int y = 0; y < 10; ++y) {
            const float* frow = fbase + (size_t)min(r0 + y, 31) * 8192;
            float a4 = Aw[4][y], a5 = Aw[5][y], a6 = Aw[6][y];
            #pragma unroll
            for (int x = 0; x < 10; ++x) {
                float fv = frow[xoff[x]];
                t[0][x] += a4 * fv;
                t[1][x] += a5 * fv;
                t[2][x] += a6 * fv;
            }
        }
        #pragma unroll
        for (int oy = 0; oy < 3; ++oy)
            #pragma unroll
            for (int ox = 0; ox < 7; ++ox) {
                float o = 0.f;
                #pragma unroll
                for (int x = 0; x < 10; ++x) o += Bw[ox][x] * t[oy][x];
                outbuf[ch * 49 + (4 + oy) * 7 + ox] = f2bf(o);
            }
    }
    __syncthreads();
    const uint4* src = (const uint4*)outbuf;
    uint4* dst = (uint4*)(pooled + (size_t)roi * 12544);
    #pragma unroll
    for (int i = 0; i < 4; ++i) {
        int idx = i * 512 + tid;
        if (idx < 1568) dst[idx] = src[idx];
    }
}

template<bool OUT_BF16>
__global__ __launch_bounds__(256) void gemm_bt(
    const ushort* __restrict__ A, const ushort* __restrict__ Bm,
    const float* __restrict__ bias, void* __restrict__ Cout,
    int M, int N, int K, int relu)
{
    constexpr int BM = 128, BN = 64, BK = 32;
    __shared__ __align__(16) ushort lA[BM][BK];
    __shared__ __align__(16) ushort lB[BN][BK];
    const int tid = threadIdx.x;
    const int m0 = blockIdx.y * BM;
    const int n0 = blockIdx.x * BN;
    const int w = tid >> 6, l = tid & 63;
    const int wr = w >> 1, wcid = w & 1;
    const int lrow = l & 15, lk = (l >> 4) * 8;

    f32x4 acc[4][2] = {};

    for (int k0 = 0; k0 < K; k0 += BK) {
        __syncthreads();
        #pragma unroll
        for (int i = 0; i < 2; ++i) {
            int chunk = i * 256 + tid;
            int row = chunk >> 2;
            int colb = (chunk & 3) * 16;
            load16_to_lds((const char*)(A + (size_t)(m0 + row) * K + k0) + colb, ((char*)lA) + chunk * 16);
        }
        {
            int chunk = tid;
            int row = chunk >> 2;
            int colb = (chunk & 3) * 16;
            load16_to_lds((const char*)(Bm + (size_t)(n0 + row) * K + k0) + colb, ((char*)lB) + chunk * 16);
        }
        __syncthreads();

        bf16x8 af[4], bfr[2];
        #pragma unroll
        for (int m = 0; m < 4; ++m)
            af[m] = *(const bf16x8*)&lA[wr * 64 + m * 16 + lrow][lk];
        #pragma unroll
        for (int n = 0; n < 2; ++n)
            bfr[n] = *(const bf16x8*)&lB[wcid * 32 + n * 16 + lrow][lk];
        #pragma unroll
        for (int m = 0; m < 4; ++m)
            #pragma unroll
            for (int n = 0; n < 2; ++n)
                acc[m][n] = __builtin_amdgcn_mfma_f32_16x16x32_bf16(af[m], bfr[n], acc[m][n], 0, 0, 0);
    }

    const int r4 = (l >> 4) * 4;
    const int cc = l & 15;
    #pragma unroll
    for (int m = 0; m < 4; ++m) {
        #pragma unroll
        for (int n = 0; n < 2; ++n) {
            int col = n0 + wcid * 32 + n * 16 + cc;
            float bv = bias[col];
            #pragma unroll
            for (int j = 0; j < 4; ++j) {
                int row = m0 + wr * 64 + m * 16 + r4 + j;
                float v = acc[m][n][j] + bv;
                if (relu) v = fmaxf(v, 0.f);
                if (OUT_BF16) ((ushort*)Cout)[(size_t)row * N + col] = f2bf(v);
                else          ((float*)Cout)[(size_t)row * N + col] = v;
            }
        }
    }
}

__global__ __launch_bounds__(256) void heads_kernel(
    const float* __restrict__ x2,
    const float* __restrict__ wc, const float* __restrict__ bc,
    const float* __restrict__ wb, const float* __restrict__ bb,
    float* __restrict__ out)
{
    int w = threadIdx.x >> 6, l = threadIdx.x & 63;
    int row = blockIdx.x * 4 + w;
    const float* xr = x2 + (size_t)row * 1024;
    float acc[10];
    #pragma unroll
    for (int o = 0; o < 10; ++o) acc[o] = 0.f;
    for (int i = 0; i < 16; ++i) {
        int k = i * 64 + l;
        float xv = xr[k];
        #pragma unroll
        for (int o = 0; o < 2; ++o) acc[o] += xv * wc[o * 1024 + k];
        #pragma unroll
        for (int o = 0; o < 8; ++o) acc[2 + o] += xv * wb[o * 1024 + k];
    }
    #pragma unroll
    for (int o = 0; o < 10; ++o) {
        float v = acc[o];
        #pragma unroll
        for (int s = 32; s > 0; s >>= 1) v += __shfl_xor(v, s, 64);
        acc[o] = v;
    }
    if (l == 0) {
        float* cls = out;
        float* bbx = out + 2048 * 2;
        cls[row * 2 + 0] = acc[0] + bc[0];
        cls[row * 2 + 1] = acc[1] + bc[1];
        #pragma unroll
        for (int o = 0; o < 8; ++o) bbx[row * 8 + o] = acc[2 + o] + bb[o];
    }
}

__global__ __launch_bounds__(256) void decode_kernel(
    const float* __restrict__ props, float* __restrict__ out)
{
    int r = blockIdx.x * 256 + threadIdx.x;
    if (r >= 2048) return;
    const float* cls = out;
    const float* bbx = out + 4096;
    float* boxes  = out + 20480;
    float* scores = out + 36864;
    float px1 = props[r * 4 + 0], py1 = props[r * 4 + 1];
    float px2 = props[r * 4 + 2], py2 = props[r * 4 + 3];
    float pw = px2 - px1, ph = py2 - py1;
    float cx = px1 + 0.5f * pw, cy = py1 + 0.5f * ph;
    const float CLIP = 4.135166556742356f;
    #pragma unroll
    for (int k = 0; k < 2; ++k) {
        float dx = bbx[r * 8 + k * 4 + 0] * 0.1f;
        float dy = bbx[r * 8 + k * 4 + 1] * 0.1f;
        float dw = fminf(bbx[r * 8 + k * 4 + 2] * 0.2f, CLIP);
        float dh = fminf(bbx[r * 8 + k * 4 + 3] * 0.2f, CLIP);
        float pcx = dx * pw + cx, pcy = dy * ph + cy;
        float ppw = expf(dw) * pw, pph = expf(dh) * ph;
        float v0 = pcx - 0.5f * ppw, v1 = pcy - 0.5f * pph;
        float v2 = pcx + 0.5f * ppw, v3 = pcy + 0.5f * pph;
        boxes[r * 8 + k * 4 + 0] = fminf(fmaxf(v0, 0.f), 1024.f);
        boxes[r * 8 + k * 4 + 1] = fminf(fmaxf(v1, 0.f), 1024.f);
        boxes[r * 8 + k * 4 + 2] = fminf(fmaxf(v2, 0.f), 1024.f);
        boxes[r * 8 + k * 4 + 3] = fminf(fmaxf(v3, 0.f), 1024.f);
    }
    float s0 = cls[r * 2], s1 = cls[r * 2 + 1];
    float m = fmaxf(s0, s1);
    float e0 = expf(s0 - m), e1 = expf(s1 - m);
    float inv = 1.f / (e0 + e1);
    scores[r * 2 + 0] = e0 * inv;
    scores[r * 2 + 1] = e1 * inv;
}

// ---------- launch ----------
extern "C" void kernel_launch(void* const* d_in, const int* in_sizes, int n_in,
                              void* d_out, int out_size, void* d_ws, size_t ws_size,
                              hipStream_t stream) {
    const float* feat  = (const float*)d_in[0];
    const float* props = (const float*)d_in[1];
    const float* w1    = (const float*)d_in[2];
    const float* b1    = (const float*)d_in[3];
    const float* w2    = (const float*)d_in[4];
    const float* b2    = (const float*)d_in[5];
    const float* wc    = (const float*)d_in[6];
    const float* bc    = (const float*)d_in[7];
    const float* wb    = (const float*)d_in[8];
    const float* bb    = (const float*)d_in[9];
    float* out = (float*)d_out;

    char* ws = (char*)d_ws;
    ushort* pooled = (ushort*)(ws);                          // 51,380,224 B
    ushort* w1b    = (ushort*)(ws + 51380224);               // 25,690,112 B
    ushort* w2b    = (ushort*)(ws + 51380224 + 25690112);    //  2,097,152 B
    ushort* x1     = (ushort*)(ws + 79167488);               //  4,194,304 B
    float*  x2     = (float*) (ws + 83361792);               //  8,388,608 B (fallback only)
    float*  featT  = (float*) (ws + 83361792);               // aliases x2 (dead by gemm2)
    float*  part   = (float*) (ws + 91750400);               // split-K partials
    const size_t WS_NEED14 = 91750400 + (size_t)14 * 8388608; // splitK=14: 117.4 MB
    const size_t WS_NEED8  = 91750400 + 67108864;             // splitK=8:  67.1 MB
    const size_t WS_NEED4  = 91750400 + 33554432;             // splitK=4:  33.5 MB

    const int M = 2048, N = 1024;
    const int MN = M * N;

    transpose_feat_kernel<<<512, 256, 0, stream>>>(feat, featT);

    if (ws_size >= WS_NEED4) {
        roi_conv_kernel<<<3744, 512, 0, stream>>>(featT, props, pooled, w1, w1b, w2, w2b);
        if (ws_size >= WS_NEED14) {
            // gemm1: splitK=14 (klen 896 = 28 steps), grid 8x16x14 = 1792 (~5 blk/CU resident, LDS-capped)
            gemm_bt_split<<<dim3(N / 128, M / 128, 14), 256, 0, stream>>>(pooled, w1b, part, M, N, 12544, 896);
            reduce_split_kernel<true ><<<MN / 1024, 256, 0, stream>>>(part, b1, x1, MN, N, 14, 1);
        } else if (ws_size >= WS_NEED8) {
            gemm_bt_split<<<dim3(N / 128, M / 128, 8), 256, 0, stream>>>(pooled, w1b, part, M, N, 12544, 1568);
            reduce_split_kernel<true ><<<MN / 1024, 256, 0, stream>>>(part, b1, x1, MN, N, 8, 1);
        } else {
            gemm_bt_split<<<dim3(N / 128, M / 128, 4), 256, 0, stream>>>(pooled, w1b, part, M, N, 12544, 3136);
            reduce_split_kernel<true ><<<MN / 1024, 256, 0, stream>>>(part, b1, x1, MN, N, 4, 1);
        }
        gemm_bt_split<<<dim3(N / 128, M / 128, 4), 256, 0, stream>>>(x1, w2b, part, M, N, 1024, 256);
        fused_tail_kernel<<<2048, 256, 0, stream>>>(part, b2, wc, bc, wb, bb, props, out, 4);
    } else {
        f32_to_bf16_kernel<<<12845056 / 2048, 256, 0, stream>>>(w1, w1b, 12845056);
        f32_to_bf16_kernel<<<1048576 / 2048, 256, 0, stream>>>(w2, w2b, 1048576);
        roi_align_kernel<<<2048, 512, 0, stream>>>(featT, props, pooled);
        gemm_bt<true ><<<dim3(N / 64, M / 128), 256, 0, stream>>>(pooled, w1b, b1, x1, M, N, 12544, 1);
        gemm_bt<false><<<dim3(N / 64, M / 128), 256, 0, stream>>>(x1, w2b, b2, x2, M, N, 1024, 1);
        heads_kernel<<<512, 256, 0, stream>>>(x2, wc, bc, wb, bb, out);
        decode_kernel<<<8, 256, 0, stream>>>(props, out);
    }
}

// Round 23
// 178.778 us; speedup vs baseline: 1.0954x; 1.0954x over previous
//
#include <hip/hip_runtime.h>
#include <hip/hip_bf16.h>
#include <stdint.h>

// ---------- common ----------
typedef __attribute__((ext_vector_type(8))) short bf16x8;
typedef __attribute__((ext_vector_type(4))) float f32x4;

__device__ __forceinline__ ushort f2bf(float f) {
    union { float f; uint32_t u; } c; c.f = f;
    uint32_t u = c.u;
    uint32_t r = (u + 0x7FFFu + ((u >> 16) & 1u)) >> 16;
    return (ushort)r;
}

__device__ __forceinline__ void load16_to_lds(const void* gsrc, void* ldst) {
    __builtin_amdgcn_global_load_lds(
        (const __attribute__((address_space(1))) uint32_t*)gsrc,
        (__attribute__((address_space(3))) uint32_t*)ldst,
        16, 0, 0);
}

// ---------- f32 -> bf16 convert (fallback path only) ----------
__global__ __launch_bounds__(256) void f32_to_bf16_kernel(
    const float* __restrict__ in, ushort* __restrict__ out, int n)
{
    int i = (blockIdx.x * 256 + threadIdx.x) * 8;
    if (i >= n) return;
    float4 a = *(const float4*)(in + i);
    float4 b = *(const float4*)(in + i + 4);
    ushort4 o0, o1;
    o0.x = f2bf(a.x); o0.y = f2bf(a.y); o0.z = f2bf(a.z); o0.w = f2bf(a.w);
    o1.x = f2bf(b.x); o1.y = f2bf(b.y); o1.z = f2bf(b.z); o1.w = f2bf(b.w);
    *(ushort4*)(out + i) = o0;
    *(ushort4*)(out + i + 4) = o1;
}

// ---------- feature transpose: [2,256,32,32] -> [2,32,32,256] ----------
__global__ __launch_bounds__(256) void transpose_feat_kernel(
    const float* __restrict__ feat, float* __restrict__ featT)
{
    int bc = blockIdx.x;
    int b = bc >> 8;
    int c = bc & 255;
    const float* src = feat + (size_t)bc * 1024;
    float* dst = featT + (size_t)b * 262144 + c;
    #pragma unroll
    for (int i = 0; i < 4; ++i) {
        int p = i * 256 + threadIdx.x;
        dst[(size_t)p * 256] = src[p];
    }
}

// ---------- fused ROI align (separable) + weight converts ----------
__global__ __launch_bounds__(512) void roi_conv_kernel(
    const float* __restrict__ featT, const float* __restrict__ props,
    ushort* __restrict__ pooled,
    const float* __restrict__ w1, ushort* __restrict__ w1b,
    const float* __restrict__ w2, ushort* __restrict__ w2b)
{
    __shared__ int   si0[28];
    __shared__ int   si1[28];
    __shared__ float sl[28];
    __shared__ float sv[28];
    __shared__ float Aw[7][10];
    __shared__ float Bw[7][10];
    __shared__ __align__(16) ushort outbuf[12544];
    const int tid = threadIdx.x;
    const int blk = blockIdx.x;

    if (blk >= 2048) {
        const float* src;
        ushort* dst;
        int base;
        if (blk < 2048 + 1568) { src = w1; dst = w1b; base = (blk - 2048) * 8192; }
        else                   { src = w2; dst = w2b; base = (blk - 3616) * 8192; }
        int i = base + tid * 16;
        #pragma unroll
        for (int h = 0; h < 2; ++h) {
            float4 a = *(const float4*)(src + i + h * 8);
            float4 b = *(const float4*)(src + i + h * 8 + 4);
            ushort4 o0, o1;
            o0.x = f2bf(a.x); o0.y = f2bf(a.y); o0.z = f2bf(a.z); o0.w = f2bf(a.w);
            o1.x = f2bf(b.x); o1.y = f2bf(b.y); o1.z = f2bf(b.z); o1.w = f2bf(b.w);
            *(ushort4*)(dst + i + h * 8) = o0;
            *(ushort4*)(dst + i + h * 8 + 4) = o1;
        }
        return;
    }

    const int roi = blk;
    const int b = roi >> 10;
    if (tid < 28) {
        int axis = (tid >= 14) ? 1 : 0;
        int pp = tid - axis * 14;
        float c0 = props[roi * 4 + (axis ? 0 : 1)] * (1.f / 32.f);
        float c1 = props[roi * 4 + (axis ? 2 : 3)] * (1.f / 32.f);
        float sz = fmaxf(c1 - c0, 1.f);
        float bsz = sz * (1.f / 7.f);
        float g = (float)(pp >> 1) + ((float)(pp & 1) + 0.5f) * 0.5f;
        float c = c0 + g * bsz;
        float valid = (c > -1.f && c < 32.f) ? 1.f : 0.f;
        float cc = fminf(fmaxf(c, 0.f), 31.f);
        float fl = floorf(cc);
        int i0 = (int)fl;
        si0[tid] = i0;
        si1[tid] = min(i0 + 1, 31);
        sl[tid] = cc - fl;
        sv[tid] = valid;
    }
    __syncthreads();

    const int r0 = si0[0];
    const int c0 = si0[14];

    if (tid < 140) {
        int axis = tid / 70;
        int e = tid - axis * 70;
        int oy = e / 10, yy = e - oy * 10;
        int base = axis * 14;
        int org = axis ? c0 : r0;
        float wsum = 0.f;
        #pragma unroll
        for (int s = 0; s < 2; ++s) {
            int p = base + oy * 2 + s;
            float w = 0.f;
            if (si0[p] - org == yy) w += 1.f - sl[p];
            if (si1[p] - org == yy) w += sl[p];
            wsum += sv[p] * w;
        }
        wsum *= 0.5f;
        if (axis == 0) Aw[oy][yy] = wsum;
        else           Bw[oy][yy] = wsum;
    }
    __syncthreads();

    const int grp = tid >> 8;
    const int ch = tid & 255;
    const float* fbase = featT + (size_t)b * 262144 + ch;

    int xoff[10];
    #pragma unroll
    for (int x = 0; x < 10; ++x) xoff[x] = min(c0 + x, 31) * 256;

    if (grp == 0) {
        float t[4][10];
        #pragma unroll
        for (int oy = 0; oy < 4; ++oy)
            #pragma unroll
            for (int x = 0; x < 10; ++x) t[oy][x] = 0.f;
        #pragma unroll
        for (int y = 0; y < 10; ++y) {
            const float* frow = fbase + (size_t)min(r0 + y, 31) * 8192;
            float a0 = Aw[0][y], a1 = Aw[1][y], a2 = Aw[2][y], a3 = Aw[3][y];
            #pragma unroll
            for (int x = 0; x < 10; ++x) {
                float fv = frow[xoff[x]];
                t[0][x] += a0 * fv;
                t[1][x] += a1 * fv;
                t[2][x] += a2 * fv;
                t[3][x] += a3 * fv;
            }
        }
        #pragma unroll
        for (int oy = 0; oy < 4; ++oy)
            #pragma unroll
            for (int ox = 0; ox < 7; ++ox) {
                float o = 0.f;
                #pragma unroll
                for (int x = 0; x < 10; ++x) o += Bw[ox][x] * t[oy][x];
                outbuf[ch * 49 + oy * 7 + ox] = f2bf(o);
            }
    } else {
        float t[3][10];
        #pragma unroll
        for (int oy = 0; oy < 3; ++oy)
            #pragma unroll
            for (int x = 0; x < 10; ++x) t[oy][x] = 0.f;
        #pragma unroll
        for (int y = 0; y < 10; ++y) {
            const float* frow = fbase + (size_t)min(r0 + y, 31) * 8192;
            float a4 = Aw[4][y], a5 = Aw[5][y], a6 = Aw[6][y];
            #pragma unroll
            for (int x = 0; x < 10; ++x) {
                float fv = frow[xoff[x]];
                t[0][x] += a4 * fv;
                t[1][x] += a5 * fv;
                t[2][x] += a6 * fv;
            }
        }
        #pragma unroll
        for (int oy = 0; oy < 3; ++oy)
            #pragma unroll
            for (int ox = 0; ox < 7; ++ox) {
                float o = 0.f;
                #pragma unroll
                for (int x = 0; x < 10; ++x) o += Bw[ox][x] * t[oy][x];
                outbuf[ch * 49 + (4 + oy) * 7 + ox] = f2bf(o);
            }
    }
    __syncthreads();

    const uint4* src = (const uint4*)outbuf;
    uint4* dst = (uint4*)(pooled + (size_t)roi * 12544);
    #pragma unroll
    for (int i = 0; i < 4; ++i) {
        int idx = i * 512 + tid;
        if (idx < 1568) dst[idx] = src[idx];
    }
}

// ---------- split-K GEMM, BK=32, double-buffered 2-phase (R12-proven) ----------
__global__ __launch_bounds__(256) void gemm_bt_split(
    const ushort* __restrict__ A, const ushort* __restrict__ Bm,
    float* __restrict__ part, int M, int N, int K, int klen)
{
    constexpr int BK = 32;
    __shared__ __align__(16) ushort lA[2][128][BK];
    __shared__ __align__(16) ushort lB[2][128][BK];
    const int tid = threadIdx.x;

    const int nbx = gridDim.x, nby = gridDim.y;
    const int nwg = nbx * nby * gridDim.z;
    const int d = blockIdx.x + nbx * (blockIdx.y + nby * blockIdx.z);
    const int t = (d & 7) * (nwg >> 3) + (d >> 3);
    const int n_blk = t % nbx;
    const int m_blk = (t / nbx) % nby;
    const int k_blk = t / (nbx * nby);

    const int m0 = m_blk * 128;
    const int n0 = n_blk * 128;
    const int k_start = k_blk * klen;

    const int w = tid >> 6, l = tid & 63;
    const int wr = w >> 1, wcid = w & 1;
    const int lrow = l & 15;
    const int lkb = (((l >> 4) ^ ((lrow >> 1) & 3)) * 16);

    const int sc0 = tid, sc1 = 256 + tid;
    const int srow0 = sc0 >> 2, srow1 = sc1 >> 2;
    const int scol0 = ((sc0 & 3) ^ ((srow0 >> 1) & 3)) * 16;
    const int scol1 = ((sc1 & 3) ^ ((srow1 >> 1) & 3)) * 16;

    const int nsteps = klen / BK;

    {
        int k0 = k_start;
        load16_to_lds((const char*)(A + (size_t)(m0 + srow0) * K + k0) + scol0, ((char*)lA[0]) + sc0 * 16);
        load16_to_lds((const char*)(A + (size_t)(m0 + srow1) * K + k0) + scol1, ((char*)lA[0]) + sc1 * 16);
        load16_to_lds((const char*)(Bm + (size_t)(n0 + srow0) * K + k0) + scol0, ((char*)lB[0]) + sc0 * 16);
        load16_to_lds((const char*)(Bm + (size_t)(n0 + srow1) * K + k0) + scol1, ((char*)lB[0]) + sc1 * 16);
    }
    __syncthreads();

    f32x4 acc[4][4] = {};
    int cur = 0;

    for (int ts = 0; ts < nsteps; ++ts) {
        if (ts + 1 < nsteps) {
            int k0 = k_start + (ts + 1) * BK;
            int nxt = cur ^ 1;
            load16_to_lds((const char*)(A + (size_t)(m0 + srow0) * K + k0) + scol0, ((char*)lA[nxt]) + sc0 * 16);
            load16_to_lds((const char*)(A + (size_t)(m0 + srow1) * K + k0) + scol1, ((char*)lA[nxt]) + sc1 * 16);
            load16_to_lds((const char*)(Bm + (size_t)(n0 + srow0) * K + k0) + scol0, ((char*)lB[nxt]) + sc0 * 16);
            load16_to_lds((const char*)(Bm + (size_t)(n0 + srow1) * K + k0) + scol1, ((char*)lB[nxt]) + sc1 * 16);
        }

        bf16x8 af[4], bfr[4];
        #pragma unroll
        for (int m = 0; m < 4; ++m)
            af[m] = *(const bf16x8*)(((const char*)lA[cur]) + (wr * 64 + m * 16 + lrow) * 64 + lkb);
        #pragma unroll
        for (int n = 0; n < 4; ++n)
            bfr[n] = *(const bf16x8*)(((const char*)lB[cur]) + (wcid * 64 + n * 16 + lrow) * 64 + lkb);
        #pragma unroll
        for (int m = 0; m < 4; ++m)
            #pragma unroll
            for (int n = 0; n < 4; ++n)
                acc[m][n] = __builtin_amdgcn_mfma_f32_16x16x32_bf16(af[m], bfr[n], acc[m][n], 0, 0, 0);

        __syncthreads();
        cur ^= 1;
    }

    const int r4 = (l >> 4) * 4;
    const int cc = l & 15;
    float* pb = part + (size_t)k_blk * M * N;
    #pragma unroll
    for (int m = 0; m < 4; ++m) {
        #pragma unroll
        for (int n = 0; n < 4; ++n) {
            int col = n0 + wcid * 64 + n * 16 + cc;
            #pragma unroll
            for (int j = 0; j < 4; ++j) {
                int row = m0 + wr * 64 + m * 16 + r4 + j;
                pb[(size_t)row * N + col] = acc[m][n][j];
            }
        }
    }
}

// ---------- reduce split-K partials + bias + relu + bf16 cast (x1) ----------
template<bool OUT_BF16>
__global__ __launch_bounds__(256) void reduce_split_kernel(
    const float* __restrict__ part, const float* __restrict__ bias,
    void* __restrict__ out, int MN, int N, int S, int relu)
{
    int i4 = (blockIdx.x * 256 + threadIdx.x) * 4;
    if (i4 >= MN) return;
    float4 a = *(const float4*)(part + i4);
    for (int s = 1; s < S; ++s) {
        float4 b = *(const float4*)(part + (size_t)s * MN + i4);
        a.x += b.x; a.y += b.y; a.z += b.z; a.w += b.w;
    }
    int bc = i4 & (N - 1);
    float4 bv = *(const float4*)(bias + bc);
    a.x += bv.x; a.y += bv.y; a.z += bv.z; a.w += bv.w;
    if (relu) {
        a.x = fmaxf(a.x, 0.f); a.y = fmaxf(a.y, 0.f);
        a.z = fmaxf(a.z, 0.f); a.w = fmaxf(a.w, 0.f);
    }
    if (OUT_BF16) {
        ushort4 o; o.x = f2bf(a.x); o.y = f2bf(a.y); o.z = f2bf(a.z); o.w = f2bf(a.w);
        *(ushort4*)((ushort*)out + i4) = o;
    } else {
        *(float4*)((float*)out + i4) = a;
    }
}

// ---------- fused tail: reduce2 + bias + relu + heads + decode + softmax ----------
__global__ __launch_bounds__(256) void fused_tail_kernel(
    const float* __restrict__ part, const float* __restrict__ b2,
    const float* __restrict__ wc, const float* __restrict__ bc,
    const float* __restrict__ wb, const float* __restrict__ bb,
    const float* __restrict__ props, float* __restrict__ out, int S)
{
    const int row = blockIdx.x;
    const int tid = threadIdx.x;
    const int i4 = tid * 4;
    const size_t MN = 2048 * 1024;
    const float* pr = part + (size_t)row * 1024 + i4;

    float4 a = *(const float4*)pr;
    for (int s = 1; s < S; ++s) {
        float4 b = *(const float4*)(pr + (size_t)s * MN);
        a.x += b.x; a.y += b.y; a.z += b.z; a.w += b.w;
    }
    float4 bv = *(const float4*)(b2 + i4);
    a.x = fmaxf(a.x + bv.x, 0.f);
    a.y = fmaxf(a.y + bv.y, 0.f);
    a.z = fmaxf(a.z + bv.z, 0.f);
    a.w = fmaxf(a.w + bv.w, 0.f);

    float acc[10];
    #pragma unroll
    for (int o = 0; o < 10; ++o) {
        const float* wrow = (o < 2) ? (wc + o * 1024) : (wb + (o - 2) * 1024);
        float4 wv = *(const float4*)(wrow + i4);
        acc[o] = a.x * wv.x + a.y * wv.y + a.z * wv.z + a.w * wv.w;
    }
    #pragma unroll
    for (int o = 0; o < 10; ++o) {
        float v = acc[o];
        #pragma unroll
        for (int s = 32; s > 0; s >>= 1) v += __shfl_xor(v, s, 64);
        acc[o] = v;
    }

    __shared__ float red[10][4];
    const int wv = tid >> 6, ln = tid & 63;
    if (ln == 0) {
        #pragma unroll
        for (int o = 0; o < 10; ++o) red[o][wv] = acc[o];
    }
    __syncthreads();

    if (tid == 0) {
        float h[10];
        #pragma unroll
        for (int o = 0; o < 10; ++o)
            h[o] = red[o][0] + red[o][1] + red[o][2] + red[o][3];
        float cls0 = h[0] + bc[0];
        float cls1 = h[1] + bc[1];
        float bx[8];
        #pragma unroll
        for (int o = 0; o < 8; ++o) bx[o] = h[2 + o] + bb[o];

        out[row * 2 + 0] = cls0;
        out[row * 2 + 1] = cls1;
        #pragma unroll
        for (int o = 0; o < 8; ++o) out[4096 + row * 8 + o] = bx[o];

        float px1 = props[row * 4 + 0], py1 = props[row * 4 + 1];
        float px2 = props[row * 4 + 2], py2 = props[row * 4 + 3];
        float pw = px2 - px1, ph = py2 - py1;
        float cx = px1 + 0.5f * pw, cy = py1 + 0.5f * ph;
        const float CLIP = 4.135166556742356f;
        float* boxes = out + 20480;
        #pragma unroll
        for (int k = 0; k < 2; ++k) {
            float dx = bx[k * 4 + 0] * 0.1f;
            float dy = bx[k * 4 + 1] * 0.1f;
            float dw = fminf(bx[k * 4 + 2] * 0.2f, CLIP);
            float dh = fminf(bx[k * 4 + 3] * 0.2f, CLIP);
            float pcx = dx * pw + cx, pcy = dy * ph + cy;
            float ppw = expf(dw) * pw, pph = expf(dh) * ph;
            boxes[row * 8 + k * 4 + 0] = fminf(fmaxf(pcx - 0.5f * ppw, 0.f), 1024.f);
            boxes[row * 8 + k * 4 + 1] = fminf(fmaxf(pcy - 0.5f * pph, 0.f), 1024.f);
            boxes[row * 8 + k * 4 + 2] = fminf(fmaxf(pcx + 0.5f * ppw, 0.f), 1024.f);
            boxes[row * 8 + k * 4 + 3] = fminf(fmaxf(pcy + 0.5f * pph, 0.f), 1024.f);
        }
        float m = fmaxf(cls0, cls1);
        float e0 = expf(cls0 - m), e1 = expf(cls1 - m);
        float inv = 1.f / (e0 + e1);
        out[36864 + row * 2 + 0] = e0 * inv;
        out[36864 + row * 2 + 1] = e1 * inv;
    }
}

// ---------- fallback kernels (ws too small path) ----------
__global__ __launch_bounds__(512) void roi_align_kernel(
    const float* __restrict__ featT, const float* __restrict__ props,
    ushort* __restrict__ pooled)
{
    int roi = blockIdx.x;
    int b = roi >> 10;
    __shared__ int   si0[28];
    __shared__ int   si1[28];
    __shared__ float sl[28];
    __shared__ float sv[28];
    __shared__ float Aw[7][10];
    __shared__ float Bw[7][10];
    __shared__ __align__(16) ushort outbuf[12544];
    int tid = threadIdx.x;
    if (tid < 28) {
        int axis = (tid >= 14) ? 1 : 0;
        int pp = tid - axis * 14;
        float c0 = props[roi * 4 + (axis ? 0 : 1)] * (1.f / 32.f);
        float c1 = props[roi * 4 + (axis ? 2 : 3)] * (1.f / 32.f);
        float sz = fmaxf(c1 - c0, 1.f);
        float bsz = sz * (1.f / 7.f);
        float g = (float)(pp >> 1) + ((float)(pp & 1) + 0.5f) * 0.5f;
        float c = c0 + g * bsz;
        float valid = (c > -1.f && c < 32.f) ? 1.f : 0.f;
        float cc = fminf(fmaxf(c, 0.f), 31.f);
        float fl = floorf(cc);
        int i0 = (int)fl;
        si0[tid] = i0;
        si1[tid] = min(i0 + 1, 31);
        sl[tid] = cc - fl;
        sv[tid] = valid;
    }
    __syncthreads();
    const int r0 = si0[0];
    const int c0 = si0[14];
    if (tid < 140) {
        int axis = tid / 70;
        int e = tid - axis * 70;
        int oy = e / 10, yy = e - oy * 10;
        int base = axis * 14;
        int org = axis ? c0 : r0;
        float wsum = 0.f;
        #pragma unroll
        for (int s = 0; s < 2; ++s) {
            int p = base + oy * 2 + s;
            float w = 0.f;
            if (si0[p] - org == yy) w += 1.f - sl[p];
            if (si1[p] - org == yy) w += sl[p];
            wsum += sv[p] * w;
        }
        wsum *= 0.5f;
        if (axis == 0) Aw[oy][yy] = wsum;
        else           Bw[oy][yy] = wsum;
    }
    __syncthreads();
    const int grp = tid >> 8;
    const int ch = tid & 255;
    const float* fbase = featT + (size_t)b * 262144 + ch;
    int xoff[10];
    #pragma unroll
    for (int x = 0; x < 10; ++x) xoff[x] = min(c0 + x, 31) * 256;
    if (grp == 0) {
        float t[4][10];
        #pragma unroll
        for (int oy = 0; oy < 4; ++oy)
            #pragma unroll
            for (int x = 0; x < 10; ++x) t[oy][x] = 0.f;
        #pragma unroll
        for (int y = 0; y < 10; ++y) {
            const float* frow = fbase + (size_t)min(r0 + y, 31) * 8192;
            float a0 = Aw[0][y], a1 = Aw[1][y], a2 = Aw[2][y], a3 = Aw[3][y];
            #pragma unroll
            for (int x = 0; x < 10; ++x) {
                float fv = frow[xoff[x]];
                t[0][x] += a0 * fv;
                t[1][x] += a1 * fv;
                t[2][x] += a2 * fv;
                t[3][x] += a3 * fv;
            }
        }
        #pragma unroll
        for (int oy = 0; oy < 4; ++oy)
            #pragma unroll
            for (int ox = 0; ox < 7; ++ox) {
                float o = 0.f;
                #pragma unroll
                for (int x = 0; x < 10; ++x) o += Bw[ox][x] * t[oy][x];
                outbuf[ch * 49 + oy * 7 + ox] = f2bf(o);
            }
    } else {
        float t[3][10];
        #pragma unroll
        for (int oy = 0; oy < 3; ++oy)
            #pragma unroll
            for (int x = 0; x < 10; ++x) t[oy][x] = 0.f;
        #pragma unroll
        for (int y = 0; y < 10; ++y) {
            const float* frow = fbase + (size_t)min(r0 + y, 31) * 8192;
            float a4 = Aw[4][y], a5 = Aw[5][y], a6 = Aw[6][y];
            #pragma unroll
            for (int x = 0; x < 10; ++x) {
                float fv = frow[xoff[x]];
                t[0][x] += a4 * fv;
                t[1][x] += a5 * fv;
                t[2][x] += a6 * fv;
            }
        }
        #pragma unroll
        for (int oy = 0; oy < 3; ++oy)
            #pragma unroll
            for (int ox = 0; ox < 7; ++ox) {
                float o = 0.f;
                #pragma unroll
                for (int x = 0; x < 10; ++x) o += Bw[ox][x] * t[oy][x];
                outbuf[ch * 49 + (4 + oy) * 7 + ox] = f2bf(o);
            }
    }
    __syncthreads();
    const uint4* src = (const uint4*)outbuf;
    uint4* dst = (uint4*)(pooled + (size_t)roi * 12544);
    #pragma unroll
    for (int i = 0; i < 4; ++i) {
        int idx = i * 512 + tid;
        if (idx < 1568) dst[idx] = src[idx];
    }
}

template<bool OUT_BF16>
__global__ __launch_bounds__(256) void gemm_bt(
    const ushort* __restrict__ A, const ushort* __restrict__ Bm,
    const float* __restrict__ bias, void* __restrict__ Cout,
    int M, int N, int K, int relu)
{
    constexpr int BM = 128, BN = 64, BK = 32;
    __shared__ __align__(16) ushort lA[BM][BK];
    __shared__ __align__(16) ushort lB[BN][BK];
    const int tid = threadIdx.x;
    const int m0 = blockIdx.y * BM;
    const int n0 = blockIdx.x * BN;
    const int w = tid >> 6, l = tid & 63;
    const int wr = w >> 1, wcid = w & 1;
    const int lrow = l & 15, lk = (l >> 4) * 8;

    f32x4 acc[4][2] = {};

    for (int k0 = 0; k0 < K; k0 += BK) {
        __syncthreads();
        #pragma unroll
        for (int i = 0; i < 2; ++i) {
            int chunk = i * 256 + tid;
            int row = chunk >> 2;
            int colb = (chunk & 3) * 16;
            load16_to_lds((const char*)(A + (size_t)(m0 + row) * K + k0) + colb, ((char*)lA) + chunk * 16);
        }
        {
            int chunk = tid;
            int row = chunk >> 2;
            int colb = (chunk & 3) * 16;
            load16_to_lds((const char*)(Bm + (size_t)(n0 + row) * K + k0) + colb, ((char*)lB) + chunk * 16);
        }
        __syncthreads();

        bf16x8 af[4], bfr[2];
        #pragma unroll
        for (int m = 0; m < 4; ++m)
            af[m] = *(const bf16x8*)&lA[wr * 64 + m * 16 + lrow][lk];
        #pragma unroll
        for (int n = 0; n < 2; ++n)
            bfr[n] = *(const bf16x8*)&lB[wcid * 32 + n * 16 + lrow][lk];
        #pragma unroll
        for (int m = 0; m < 4; ++m)
            #pragma unroll
            for (int n = 0; n < 2; ++n)
                acc[m][n] = __builtin_amdgcn_mfma_f32_16x16x32_bf16(af[m], bfr[n], acc[m][n], 0, 0, 0);
    }

    const int r4 = (l >> 4) * 4;
    const int cc = l & 15;
    #pragma unroll
    for (int m = 0; m < 4; ++m) {
        #pragma unroll
        for (int n = 0; n < 2; ++n) {
            int col = n0 + wcid * 32 + n * 16 + cc;
            float bv = bias[col];
            #pragma unroll
            for (int j = 0; j < 4; ++j) {
                int row = m0 + wr * 64 + m * 16 + r4 + j;
                float v = acc[m][n][j] + bv;
                if (relu) v = fmaxf(v, 0.f);
                if (OUT_BF16) ((ushort*)Cout)[(size_t)row * N + col] = f2bf(v);
                else          ((float*)Cout)[(size_t)row * N + col] = v;
            }
        }
    }
}

__global__ __launch_bounds__(256) void heads_kernel(
    const float* __restrict__ x2,
    const float* __restrict__ wc, const float* __restrict__ bc,
    const float* __restrict__ wb, const float* __restrict__ bb,
    float* __restrict__ out)
{
    int w = threadIdx.x >> 6, l = threadIdx.x & 63;
    int row = blockIdx.x * 4 + w;
    const float* xr = x2 + (size_t)row * 1024;
    float acc[10];
    #pragma unroll
    for (int o = 0; o < 10; ++o) acc[o] = 0.f;
    for (int i = 0; i < 16; ++i) {
        int k = i * 64 + l;
        float xv = xr[k];
        #pragma unroll
        for (int o = 0; o < 2; ++o) acc[o] += xv * wc[o * 1024 + k];
        #pragma unroll
        for (int o = 0; o < 8; ++o) acc[2 + o] += xv * wb[o * 1024 + k];
    }
    #pragma unroll
    for (int o = 0; o < 10; ++o) {
        float v = acc[o];
        #pragma unroll
        for (int s = 32; s > 0; s >>= 1) v += __shfl_xor(v, s, 64);
        acc[o] = v;
    }
    if (l == 0) {
        float* cls = out;
        float* bbx = out + 2048 * 2;
        cls[row * 2 + 0] = acc[0] + bc[0];
        cls[row * 2 + 1] = acc[1] + bc[1];
        #pragma unroll
        for (int o = 0; o < 8; ++o) bbx[row * 8 + o] = acc[2 + o] + bb[o];
    }
}

__global__ __launch_bounds__(256) void decode_kernel(
    const float* __restrict__ props, float* __restrict__ out)
{
    int r = blockIdx.x * 256 + threadIdx.x;
    if (r >= 2048) return;
    const float* cls = out;
    const float* bbx = out + 4096;
    float* boxes  = out + 20480;
    float* scores = out + 36864;
    float px1 = props[r * 4 + 0], py1 = props[r * 4 + 1];
    float px2 = props[r * 4 + 2], py2 = props[r * 4 + 3];
    float pw = px2 - px1, ph = py2 - py1;
    float cx = px1 + 0.5f * pw, cy = py1 + 0.5f * ph;
    const float CLIP = 4.135166556742356f;
    #pragma unroll
    for (int k = 0; k < 2; ++k) {
        float dx = bbx[r * 8 + k * 4 + 0] * 0.1f;
        float dy = bbx[r * 8 + k * 4 + 1] * 0.1f;
        float dw = fminf(bbx[r * 8 + k * 4 + 2] * 0.2f, CLIP);
        float dh = fminf(bbx[r * 8 + k * 4 + 3] * 0.2f, CLIP);
        float pcx = dx * pw + cx, pcy = dy * ph + cy;
        float ppw = expf(dw) * pw, pph = expf(dh) * ph;
        float v0 = pcx - 0.5f * ppw, v1 = pcy - 0.5f * pph;
        float v2 = pcx + 0.5f * ppw, v3 = pcy + 0.5f * pph;
        boxes[r * 8 + k * 4 + 0] = fminf(fmaxf(v0, 0.f), 1024.f);
        boxes[r * 8 + k * 4 + 1] = fminf(fmaxf(v1, 0.f), 1024.f);
        boxes[r * 8 + k * 4 + 2] = fminf(fmaxf(v2, 0.f), 1024.f);
        boxes[r * 8 + k * 4 + 3] = fminf(fmaxf(v3, 0.f), 1024.f);
    }
    float s0 = cls[r * 2], s1 = cls[r * 2 + 1];
    float m = fmaxf(s0, s1);
    float e0 = expf(s0 - m), e1 = expf(s1 - m);
    float inv = 1.f / (e0 + e1);
    scores[r * 2 + 0] = e0 * inv;
    scores[r * 2 + 1] = e1 * inv;
}

// ---------- launch ----------
extern "C" void kernel_launch(void* const* d_in, const int* in_sizes, int n_in,
                              void* d_out, int out_size, void* d_ws, size_t ws_size,
                              hipStream_t stream) {
    const float* feat  = (const float*)d_in[0];
    const float* props = (const float*)d_in[1];
    const float* w1    = (const float*)d_in[2];
    const float* b1    = (const float*)d_in[3];
    const float* w2    = (const float*)d_in[4];
    const float* b2    = (const float*)d_in[5];
    const float* wc    = (const float*)d_in[6];
    const float* bc    = (const float*)d_in[7];
    const float* wb    = (const float*)d_in[8];
    const float* bb    = (const float*)d_in[9];
    float* out = (float*)d_out;

    char* ws = (char*)d_ws;
    ushort* pooled = (ushort*)(ws);                          // 51,380,224 B
    ushort* w1b    = (ushort*)(ws + 51380224);               // 25,690,112 B
    ushort* w2b    = (ushort*)(ws + 51380224 + 25690112);    //  2,097,152 B
    ushort* x1     = (ushort*)(ws + 79167488);               //  4,194,304 B
    float*  x2     = (float*) (ws + 83361792);               //  8,388,608 B (fallback only)
    float*  featT  = (float*) (ws + 83361792);               // aliases x2 (dead by gemm2)
    float*  part   = (float*) (ws + 91750400);               // split-K partials
    const size_t WS_NEED8  = 91750400 + 67108864;            // splitK=8:  67.1 MB
    const size_t WS_NEED4  = 91750400 + 33554432;            // splitK=4:  33.5 MB

    const int M = 2048, N = 1024;
    const int MN = M * N;

    transpose_feat_kernel<<<512, 256, 0, stream>>>(feat, featT);

    if (ws_size >= WS_NEED8) {
        roi_conv_kernel<<<3744, 512, 0, stream>>>(featT, props, pooled, w1, w1b, w2, w2b);
        gemm_bt_split<<<dim3(N / 128, M / 128, 8), 256, 0, stream>>>(pooled, w1b, part, M, N, 12544, 1568);
        reduce_split_kernel<true ><<<MN / 1024, 256, 0, stream>>>(part, b1, x1, MN, N, 8, 1);
        gemm_bt_split<<<dim3(N / 128, M / 128, 4), 256, 0, stream>>>(x1, w2b, part, M, N, 1024, 256);
        fused_tail_kernel<<<2048, 256, 0, stream>>>(part, b2, wc, bc, wb, bb, props, out, 4);
    } else if (ws_size >= WS_NEED4) {
        roi_conv_kernel<<<3744, 512, 0, stream>>>(featT, props, pooled, w1, w1b, w2, w2b);
        gemm_bt_split<<<dim3(N / 128, M / 128, 4), 256, 0, stream>>>(pooled, w1b, part, M, N, 12544, 3136);
        reduce_split_kernel<true ><<<MN / 1024, 256, 0, stream>>>(part, b1, x1, MN, N, 4, 1);
        gemm_bt_split<<<dim3(N / 128, M / 128, 4), 256, 0, stream>>>(x1, w2b, part, M, N, 1024, 256);
        fused_tail_kernel<<<2048, 256, 0, stream>>>(part, b2, wc, bc, wb, bb, props, out, 4);
    } else {
        f32_to_bf16_kernel<<<12845056 / 2048, 256, 0, stream>>>(w1, w1b, 12845056);
        f32_to_bf16_kernel<<<1048576 / 2048, 256, 0, stream>>>(w2, w2b, 1048576);
        roi_align_kernel<<<2048, 512, 0, stream>>>(featT, props, pooled);
        gemm_bt<true ><<<dim3(N / 64, M / 128), 256, 0, stream>>>(pooled, w1b, b1, x1, M, N, 12544, 1);
        gemm_bt<false><<<dim3(N / 64, M / 128), 256, 0, stream>>>(x1, w2b, b2, x2, M, N, 1024, 1);
        heads_kernel<<<512, 256, 0, stream>>>(x2, wc, bc, wb, bb, out);
        decode_kernel<<<8, 256, 0, stream>>>(props, out);
    }
}

// Round 26
// 171.760 us; speedup vs baseline: 1.1402x; 1.0409x over previous
//
#include <hip/hip_runtime.h>
#include <hip/hip_bf16.h>
#include <stdint.h>

// ---------- common ----------
typedef __attribute__((ext_vector_type(8))) short bf16x8;
typedef __attribute__((ext_vector_type(4))) float f32x4;

__device__ __forceinline__ ushort f2bf(float f) {
    union { float f; uint32_t u; } c; c.f = f;
    uint32_t u = c.u;
    uint32_t r = (u + 0x7FFFu + ((u >> 16) & 1u)) >> 16;
    return (ushort)r;
}

__device__ __forceinline__ void load16_to_lds(const void* gsrc, void* ldst) {
    __builtin_amdgcn_global_load_lds(
        (const __attribute__((address_space(1))) uint32_t*)gsrc,
        (__attribute__((address_space(3))) uint32_t*)ldst,
        16, 0, 0);
}

// ---------- f32 -> bf16 convert (fallback path only) ----------
__global__ __launch_bounds__(256) void f32_to_bf16_kernel(
    const float* __restrict__ in, ushort* __restrict__ out, int n)
{
    int i = (blockIdx.x * 256 + threadIdx.x) * 8;
    if (i >= n) return;
    float4 a = *(const float4*)(in + i);
    float4 b = *(const float4*)(in + i + 4);
    ushort4 o0, o1;
    o0.x = f2bf(a.x); o0.y = f2bf(a.y); o0.z = f2bf(a.z); o0.w = f2bf(a.w);
    o1.x = f2bf(b.x); o1.y = f2bf(b.y); o1.z = f2bf(b.z); o1.w = f2bf(b.w);
    *(ushort4*)(out + i) = o0;
    *(ushort4*)(out + i + 4) = o1;
}

// ---------- feature transpose: [2,256,32,32] -> [2,32,32,256] ----------
__global__ __launch_bounds__(256) void transpose_feat_kernel(
    const float* __restrict__ feat, float* __restrict__ featT)
{
    int bc = blockIdx.x;
    int b = bc >> 8;
    int c = bc & 255;
    const float* src = feat + (size_t)bc * 1024;
    float* dst = featT + (size_t)b * 262144 + c;
    #pragma unroll
    for (int i = 0; i < 4; ++i) {
        int p = i * 256 + threadIdx.x;
        dst[(size_t)p * 256] = src[p];
    }
}

// ---------- fused ROI align (separable, 4-way row split) + weight converts ----------
// 1024 threads. ROI branch: group g (tid>>8) owns output rows oy=2g,2g+1;
// accumulator is t[2][10] (20 regs) to land under the 64-VGPR occupancy
// boundary (R22: 128 VGPR capped waves at 16/CU). Convert branch: 8/thread.
__global__ __launch_bounds__(1024) void roi_conv_kernel(
    const float* __restrict__ featT, const float* __restrict__ props,
    ushort* __restrict__ pooled,
    const float* __restrict__ w1, ushort* __restrict__ w1b,
    const float* __restrict__ w2, ushort* __restrict__ w2b)
{
    __shared__ int   si0[28];
    __shared__ int   si1[28];
    __shared__ float sl[28];
    __shared__ float sv[28];
    __shared__ float Aw[7][10];
    __shared__ float Bw[7][10];
    __shared__ __align__(16) ushort outbuf[12544];
    const int tid = threadIdx.x;
    const int blk = blockIdx.x;

    if (blk >= 2048) {
        // ---- convert branch (block-uniform): 8192 elems/block, 8/thread ----
        const float* src;
        ushort* dst;
        int base;
        if (blk < 2048 + 1568) { src = w1; dst = w1b; base = (blk - 2048) * 8192; }
        else                   { src = w2; dst = w2b; base = (blk - 3616) * 8192; }
        int i = base + tid * 8;
        float4 a = *(const float4*)(src + i);
        float4 b = *(const float4*)(src + i + 4);
        ushort4 o0, o1;
        o0.x = f2bf(a.x); o0.y = f2bf(a.y); o0.z = f2bf(a.z); o0.w = f2bf(a.w);
        o1.x = f2bf(b.x); o1.y = f2bf(b.y); o1.z = f2bf(b.z); o1.w = f2bf(b.w);
        *(ushort4*)(dst + i) = o0;
        *(ushort4*)(dst + i + 4) = o1;
        return;
    }

    // ---- ROI branch ----
    const int roi = blk;
    const int b = roi >> 10;
    if (tid < 28) {
        int axis = (tid >= 14) ? 1 : 0;
        int pp = tid - axis * 14;
        float c0 = props[roi * 4 + (axis ? 0 : 1)] * (1.f / 32.f);
        float c1 = props[roi * 4 + (axis ? 2 : 3)] * (1.f / 32.f);
        float sz = fmaxf(c1 - c0, 1.f);
        float bsz = sz * (1.f / 7.f);
        float g = (float)(pp >> 1) + ((float)(pp & 1) + 0.5f) * 0.5f;
        float c = c0 + g * bsz;
        float valid = (c > -1.f && c < 32.f) ? 1.f : 0.f;
        float cc = fminf(fmaxf(c, 0.f), 31.f);
        float fl = floorf(cc);
        int i0 = (int)fl;
        si0[tid] = i0;
        si1[tid] = min(i0 + 1, 31);
        sl[tid] = cc - fl;
        sv[tid] = valid;
    }
    __syncthreads();

    const int r0 = si0[0];
    const int c0 = si0[14];

    if (tid < 140) {
        int axis = tid / 70;
        int e = tid - axis * 70;
        int oy = e / 10, yy = e - oy * 10;
        int base = axis * 14;
        int org = axis ? c0 : r0;
        float wsum = 0.f;
        #pragma unroll
        for (int s = 0; s < 2; ++s) {
            int p = base + oy * 2 + s;
            float w = 0.f;
            if (si0[p] - org == yy) w += 1.f - sl[p];
            if (si1[p] - org == yy) w += sl[p];
            wsum += sv[p] * w;
        }
        wsum *= 0.5f;
        if (axis == 0) Aw[oy][yy] = wsum;
        else           Bw[oy][yy] = wsum;
    }
    __syncthreads();

    const int grp = tid >> 8;            // 0..3 (wave-uniform)
    const int ch = tid & 255;
    const int oyA = grp * 2;             // 0,2,4,6
    const int oyB = min(oyA + 1, 6);     // 1,3,5,6 (grp3 duplicate, write guarded)
    const bool hasB = (oyA + 1) < 7;
    const float* fbase = featT + (size_t)b * 262144 + ch;

    int xoff[10];
    #pragma unroll
    for (int x = 0; x < 10; ++x) xoff[x] = min(c0 + x, 31) * 256;

    float tA[10], tB[10];
    #pragma unroll
    for (int x = 0; x < 10; ++x) { tA[x] = 0.f; tB[x] = 0.f; }

    #pragma unroll
    for (int y = 0; y < 10; ++y) {
        const float* frow = fbase + (size_t)min(r0 + y, 31) * 8192;
        float aA = Aw[oyA][y], aB = Aw[oyB][y];
        #pragma unroll
        for (int x = 0; x < 10; ++x) {
            float fv = frow[xoff[x]];
            tA[x] += aA * fv;
            tB[x] += aB * fv;
        }
    }
    #pragma unroll
    for (int ox = 0; ox < 7; ++ox) {
        float oA = 0.f, oB = 0.f;
        #pragma unroll
        for (int x = 0; x < 10; ++x) {
            float bw = Bw[ox][x];
            oA += bw * tA[x];
            oB += bw * tB[x];
        }
        outbuf[ch * 49 + oyA * 7 + ox] = f2bf(oA);
        if (hasB) outbuf[ch * 49 + (oyA + 1) * 7 + ox] = f2bf(oB);
    }
    __syncthreads();

    const uint4* src = (const uint4*)outbuf;
    uint4* dst = (uint4*)(pooled + (size_t)roi * 12544);
    #pragma unroll
    for (int i = 0; i < 2; ++i) {
        int idx = i * 1024 + tid;
        if (idx < 1568) dst[idx] = src[idx];   // 25088 B = 1568 x 16 B
    }
}

// ---------- split-K GEMM, BK=32, double-buffered 2-phase (R12-proven) ----------
__global__ __launch_bounds__(256) void gemm_bt_split(
    const ushort* __restrict__ A, const ushort* __restrict__ Bm,
    float* __restrict__ part, int M, int N, int K, int klen)
{
    constexpr int BK = 32;
    __shared__ __align__(16) ushort lA[2][128][BK];
    __shared__ __align__(16) ushort lB[2][128][BK];
    const int tid = threadIdx.x;

    const int nbx = gridDim.x, nby = gridDim.y;
    const int nwg = nbx * nby * gridDim.z;
    const int d = blockIdx.x + nbx * (blockIdx.y + nby * blockIdx.z);
    const int t = (d & 7) * (nwg >> 3) + (d >> 3);
    const int n_blk = t % nbx;
    const int m_blk = (t / nbx) % nby;
    const int k_blk = t / (nbx * nby);

    const int m0 = m_blk * 128;
    const int n0 = n_blk * 128;
    const int k_start = k_blk * klen;

    const int w = tid >> 6, l = tid & 63;
    const int wr = w >> 1, wcid = w & 1;
    const int lrow = l & 15;
    const int lkb = (((l >> 4) ^ ((lrow >> 1) & 3)) * 16);

    const int sc0 = tid, sc1 = 256 + tid;
    const int srow0 = sc0 >> 2, srow1 = sc1 >> 2;
    const int scol0 = ((sc0 & 3) ^ ((srow0 >> 1) & 3)) * 16;
    const int scol1 = ((sc1 & 3) ^ ((srow1 >> 1) & 3)) * 16;

    const int nsteps = klen / BK;

    {
        int k0 = k_start;
        load16_to_lds((const char*)(A + (size_t)(m0 + srow0) * K + k0) + scol0, ((char*)lA[0]) + sc0 * 16);
        load16_to_lds((const char*)(A + (size_t)(m0 + srow1) * K + k0) + scol1, ((char*)lA[0]) + sc1 * 16);
        load16_to_lds((const char*)(Bm + (size_t)(n0 + srow0) * K + k0) + scol0, ((char*)lB[0]) + sc0 * 16);
        load16_to_lds((const char*)(Bm + (size_t)(n0 + srow1) * K + k0) + scol1, ((char*)lB[0]) + sc1 * 16);
    }
    __syncthreads();

    f32x4 acc[4][4] = {};
    int cur = 0;

    for (int ts = 0; ts < nsteps; ++ts) {
        if (ts + 1 < nsteps) {
            int k0 = k_start + (ts + 1) * BK;
            int nxt = cur ^ 1;
            load16_to_lds((const char*)(A + (size_t)(m0 + srow0) * K + k0) + scol0, ((char*)lA[nxt]) + sc0 * 16);
            load16_to_lds((const char*)(A + (size_t)(m0 + srow1) * K + k0) + scol1, ((char*)lA[nxt]) + sc1 * 16);
            load16_to_lds((const char*)(Bm + (size_t)(n0 + srow0) * K + k0) + scol0, ((char*)lB[nxt]) + sc0 * 16);
            load16_to_lds((const char*)(Bm + (size_t)(n0 + srow1) * K + k0) + scol1, ((char*)lB[nxt]) + sc1 * 16);
        }

        bf16x8 af[4], bfr[4];
        #pragma unroll
        for (int m = 0; m < 4; ++m)
            af[m] = *(const bf16x8*)(((const char*)lA[cur]) + (wr * 64 + m * 16 + lrow) * 64 + lkb);
        #pragma unroll
        for (int n = 0; n < 4; ++n)
            bfr[n] = *(const bf16x8*)(((const char*)lB[cur]) + (wcid * 64 + n * 16 + lrow) * 64 + lkb);
        #pragma unroll
        for (int m = 0; m < 4; ++m)
            #pragma unroll
            for (int n = 0; n < 4; ++n)
                acc[m][n] = __builtin_amdgcn_mfma_f32_16x16x32_bf16(af[m], bfr[n], acc[m][n], 0, 0, 0);

        __syncthreads();
        cur ^= 1;
    }

    const int r4 = (l >> 4) * 4;
    const int cc = l & 15;
    float* pb = part + (size_t)k_blk * M * N;
    #pragma unroll
    for (int m = 0; m < 4; ++m) {
        #pragma unroll
        for (int n = 0; n < 4; ++n) {
            int col = n0 + wcid * 64 + n * 16 + cc;
            #pragma unroll
            for (int j = 0; j < 4; ++j) {
                int row = m0 + wr * 64 + m * 16 + r4 + j;
                pb[(size_t)row * N + col] = acc[m][n][j];
            }
        }
    }
}

// ---------- reduce split-K partials + bias + relu + bf16 cast (x1) ----------
template<bool OUT_BF16>
__global__ __launch_bounds__(256) void reduce_split_kernel(
    const float* __restrict__ part, const float* __restrict__ bias,
    void* __restrict__ out, int MN, int N, int S, int relu)
{
    int i4 = (blockIdx.x * 256 + threadIdx.x) * 4;
    if (i4 >= MN) return;
    float4 a = *(const float4*)(part + i4);
    for (int s = 1; s < S; ++s) {
        float4 b = *(const float4*)(part + (size_t)s * MN + i4);
        a.x += b.x; a.y += b.y; a.z += b.z; a.w += b.w;
    }
    int bc = i4 & (N - 1);
    float4 bv = *(const float4*)(bias + bc);
    a.x += bv.x; a.y += bv.y; a.z += bv.z; a.w += bv.w;
    if (relu) {
        a.x = fmaxf(a.x, 0.f); a.y = fmaxf(a.y, 0.f);
        a.z = fmaxf(a.z, 0.f); a.w = fmaxf(a.w, 0.f);
    }
    if (OUT_BF16) {
        ushort4 o; o.x = f2bf(a.x); o.y = f2bf(a.y); o.z = f2bf(a.z); o.w = f2bf(a.w);
        *(ushort4*)((ushort*)out + i4) = o;
    } else {
        *(float4*)((float*)out + i4) = a;
    }
}

// ---------- fused tail: reduce2 + bias + relu + heads + decode + softmax ----------
__global__ __launch_bounds__(256) void fused_tail_kernel(
    const float* __restrict__ part, const float* __restrict__ b2,
    const float* __restrict__ wc, const float* __restrict__ bc,
    const float* __restrict__ wb, const float* __restrict__ bb,
    const float* __restrict__ props, float* __restrict__ out, int S)
{
    const int row = blockIdx.x;
    const int tid = threadIdx.x;
    const int i4 = tid * 4;
    const size_t MN = 2048 * 1024;
    const float* pr = part + (size_t)row * 1024 + i4;

    float4 a = *(const float4*)pr;
    for (int s = 1; s < S; ++s) {
        float4 b = *(const float4*)(pr + (size_t)s * MN);
        a.x += b.x; a.y += b.y; a.z += b.z; a.w += b.w;
    }
    float4 bv = *(const float4*)(b2 + i4);
    a.x = fmaxf(a.x + bv.x, 0.f);
    a.y = fmaxf(a.y + bv.y, 0.f);
    a.z = fmaxf(a.z + bv.z, 0.f);
    a.w = fmaxf(a.w + bv.w, 0.f);

    float acc[10];
    #pragma unroll
    for (int o = 0; o < 10; ++o) {
        const float* wrow = (o < 2) ? (wc + o * 1024) : (wb + (o - 2) * 1024);
        float4 wv = *(const float4*)(wrow + i4);
        acc[o] = a.x * wv.x + a.y * wv.y + a.z * wv.z + a.w * wv.w;
    }
    #pragma unroll
    for (int o = 0; o < 10; ++o) {
        float v = acc[o];
        #pragma unroll
        for (int s = 32; s > 0; s >>= 1) v += __shfl_xor(v, s, 64);
        acc[o] = v;
    }

    __shared__ float red[10][4];
    const int wv = tid >> 6, ln = tid & 63;
    if (ln == 0) {
        #pragma unroll
        for (int o = 0; o < 10; ++o) red[o][wv] = acc[o];
    }
    __syncthreads();

    if (tid == 0) {
        float h[10];
        #pragma unroll
        for (int o = 0; o < 10; ++o)
            h[o] = red[o][0] + red[o][1] + red[o][2] + red[o][3];
        float cls0 = h[0] + bc[0];
        float cls1 = h[1] + bc[1];
        float bx[8];
        #pragma unroll
        for (int o = 0; o < 8; ++o) bx[o] = h[2 + o] + bb[o];

        out[row * 2 + 0] = cls0;
        out[row * 2 + 1] = cls1;
        #pragma unroll
        for (int o = 0; o < 8; ++o) out[4096 + row * 8 + o] = bx[o];

        float px1 = props[row * 4 + 0], py1 = props[row * 4 + 1];
        float px2 = props[row * 4 + 2], py2 = props[row * 4 + 3];
        float pw = px2 - px1, ph = py2 - py1;
        float cx = px1 + 0.5f * pw, cy = py1 + 0.5f * ph;
        const float CLIP = 4.135166556742356f;
        float* boxes = out + 20480;
        #pragma unroll
        for (int k = 0; k < 2; ++k) {
            float dx = bx[k * 4 + 0] * 0.1f;
            float dy = bx[k * 4 + 1] * 0.1f;
            float dw = fminf(bx[k * 4 + 2] * 0.2f, CLIP);
            float dh = fminf(bx[k * 4 + 3] * 0.2f, CLIP);
            float pcx = dx * pw + cx, pcy = dy * ph + cy;
            float ppw = expf(dw) * pw, pph = expf(dh) * ph;
            boxes[row * 8 + k * 4 + 0] = fminf(fmaxf(pcx - 0.5f * ppw, 0.f), 1024.f);
            boxes[row * 8 + k * 4 + 1] = fminf(fmaxf(pcy - 0.5f * pph, 0.f), 1024.f);
            boxes[row * 8 + k * 4 + 2] = fminf(fmaxf(pcx + 0.5f * ppw, 0.f), 1024.f);
            boxes[row * 8 + k * 4 + 3] = fminf(fmaxf(pcy + 0.5f * pph, 0.f), 1024.f);
        }
        float m = fmaxf(cls0, cls1);
        float e0 = expf(cls0 - m), e1 = expf(cls1 - m);
        float inv = 1.f / (e0 + e1);
        out[36864 + row * 2 + 0] = e0 * inv;
        out[36864 + row * 2 + 1] = e1 * inv;
    }
}

// ---------- fallback kernels (ws too small path) ----------
__global__ __launch_bounds__(512) void roi_align_kernel(
    const float* __restrict__ featT, const float* __restrict__ props,
    ushort* __restrict__ pooled)
{
    int roi = blockIdx.x;
    int b = roi >> 10;
    __shared__ int   si0[28];
    __shared__ int   si1[28];
    __shared__ float sl[28];
    __shared__ float sv[28];
    __shared__ float Aw[7][10];
    __shared__ float Bw[7][10];
    __shared__ __align__(16) ushort outbuf[12544];
    int tid = threadIdx.x;
    if (tid < 28) {
        int axis = (tid >= 14) ? 1 : 0;
        int pp = tid - axis * 14;
        float c0 = props[roi * 4 + (axis ? 0 : 1)] * (1.f / 32.f);
        float c1 = props[roi * 4 + (axis ? 2 : 3)] * (1.f / 32.f);
        float sz = fmaxf(c1 - c0, 1.f);
        float bsz = sz * (1.f / 7.f);
        float g = (float)(pp >> 1) + ((float)(pp & 1) + 0.5f) * 0.5f;
        float c = c0 + g * bsz;
        float valid = (c > -1.f && c < 32.f) ? 1.f : 0.f;
        float cc = fminf(fmaxf(c, 0.f), 31.f);
        float fl = floorf(cc);
        int i0 = (int)fl;
        si0[tid] = i0;
        si1[tid] = min(i0 + 1, 31);
        sl[tid] = cc - fl;
        sv[tid] = valid;
    }
    __syncthreads();
    const int r0 = si0[0];
    const int c0 = si0[14];
    if (tid < 140) {
        int axis = tid / 70;
        int e = tid - axis * 70;
        int oy = e / 10, yy = e - oy * 10;
        int base = axis * 14;
        int org = axis ? c0 : r0;
        float wsum = 0.f;
        #pragma unroll
        for (int s = 0; s < 2; ++s) {
            int p = base + oy * 2 + s;
            float w = 0.f;
            if (si0[p] - org == yy) w += 1.f - sl[p];
            if (si1[p] - org == yy) w += sl[p];
            wsum += sv[p] * w;
        }
        wsum *= 0.5f;
        if (axis == 0) Aw[oy][yy] = wsum;
        else           Bw[oy][yy] = wsum;
    }
    __syncthreads();
    const int grp = tid >> 8;
    const int ch = tid & 255;
    const float* fbase = featT + (size_t)b * 262144 + ch;
    int xoff[10];
    #pragma unroll
    for (int x = 0; x < 10; ++x) xoff[x] = min(c0 + x, 31) * 256;
    if (grp == 0) {
        float t[4][10];
        #pragma unroll
        for (int oy = 0; oy < 4; ++oy)
            #pragma unroll
            for (int x = 0; x < 10; ++x) t[oy][x] = 0.f;
        #pragma unroll
        for (int y = 0; y < 10; ++y) {
            const float* frow = fbase + (size_t)min(r0 + y, 31) * 8192;
            float a0 = Aw[0][y], a1 = Aw[1][y], a2 = Aw[2][y], a3 = Aw[3][y];
            #pragma unroll
            for (int x = 0; x < 10; ++x) {
                float fv = frow[xoff[x]];
                t[0][x] += a0 * fv;
                t[1][x] += a1 * fv;
                t[2][x] += a2 * fv;
                t[3][x] += a3 * fv;
            }
        }
        #pragma unroll
        for (int oy = 0; oy < 4; ++oy)
            #pragma unroll
            for (int ox = 0; ox < 7; ++ox) {
                float o = 0.f;
                #pragma unroll
                for (int x = 0; x < 10; ++x) o += Bw[ox][x] * t[oy][x];
                outbuf[ch * 49 + oy * 7 + ox] = f2bf(o);
            }
    } else {
        float t[3][10];
        #pragma unroll
        for (int oy = 0; oy < 3; ++oy)
            #pragma unroll
            for (int x = 0; x < 10; ++x) t[oy][x] = 0.f;
        #pragma unroll
        for (int y = 0; y < 10; ++y) {
            const float* frow = fbase + (size_t)min(r0 + y, 31) * 8192;
            float a4 = Aw[4][y], a5 = Aw[5][y], a6 = Aw[6][y];
            #pragma unroll
            for (int x = 0; x < 10; ++x) {
                float fv = frow[xoff[x]];
                t[0][x] += a4 * fv;
                t[1][x] += a5 * fv;
                t[2][x] += a6 * fv;
            }
        }
        #pragma unroll
        for (int oy = 0; oy < 3; ++oy)
            #pragma unroll
            for (int ox = 0; ox < 7; ++ox) {
                float o = 0.f;
                #pragma unroll
                for (int x = 0; x < 10; ++x) o += Bw[ox][x] * t[oy][x];
                outbuf[ch * 49 + (4 + oy) * 7 + ox] = f2bf(o);
            }
    }
    __syncthreads();
    const uint4* src = (const uint4*)outbuf;
    uint4* dst = (uint4*)(pooled + (size_t)roi * 12544);
    #pragma unroll
    for (int i = 0; i < 4; ++i) {
        int idx = i * 512 + tid;
        if (idx < 1568) dst[idx] = src[idx];
    }
}

template<bool OUT_BF16>
__global__ __launch_bounds__(256) void gemm_bt(
    const ushort* __restrict__ A, const ushort* __restrict__ Bm,
    const float* __restrict__ bias, void* __restrict__ Cout,
    int M, int N, int K, int relu)
{
    constexpr int BM = 128, BN = 64, BK = 32;
    __shared__ __align__(16) ushort lA[BM][BK];
    __shared__ __align__(16) ushort lB[BN][BK];
    const int tid = threadIdx.x;
    const int m0 = blockIdx.y * BM;
    const int n0 = blockIdx.x * BN;
    const int w = tid >> 6, l = tid & 63;
    const int wr = w >> 1, wcid = w & 1;
    const int lrow = l & 15, lk = (l >> 4) * 8;

    f32x4 acc[4][2] = {};

    for (int k0 = 0; k0 < K; k0 += BK) {
        __syncthreads();
        #pragma unroll
        for (int i = 0; i < 2; ++i) {
            int chunk = i * 256 + tid;
            int row = chunk >> 2;
            int colb = (chunk & 3) * 16;
            load16_to_lds((const char*)(A + (size_t)(m0 + row) * K + k0) + colb, ((char*)lA) + chunk * 16);
        }
        {
            int chunk = tid;
            int row = chunk >> 2;
            int colb = (chunk & 3) * 16;
            load16_to_lds((const char*)(Bm + (size_t)(n0 + row) * K + k0) + colb, ((char*)lB) + chunk * 16);
        }
        __syncthreads();

        bf16x8 af[4], bfr[2];
        #pragma unroll
        for (int m = 0; m < 4; ++m)
            af[m] = *(const bf16x8*)&lA[wr * 64 + m * 16 + lrow][lk];
        #pragma unroll
        for (int n = 0; n < 2; ++n)
            bfr[n] = *(const bf16x8*)&lB[wcid * 32 + n * 16 + lrow][lk];
        #pragma unroll
        for (int m = 0; m < 4; ++m)
            #pragma unroll
            for (int n = 0; n < 2; ++n)
                acc[m][n] = __builtin_amdgcn_mfma_f32_16x16x32_bf16(af[m], bfr[n], acc[m][n], 0, 0, 0);
    }

    const int r4 = (l >> 4) * 4;
    const int cc = l & 15;
    #pragma unroll
    for (int m = 0; m < 4; ++m) {
        #pragma unroll
        for (int n = 0; n < 2; ++n) {
            int col = n0 + wcid * 32 + n * 16 + cc;
            float bv = bias[col];
            #pragma unroll
            for (int j = 0; j < 4; ++j) {
                int row = m0 + wr * 64 + m * 16 + r4 + j;
                float v = acc[m][n][j] + bv;
                if (relu) v = fmaxf(v, 0.f);
                if (OUT_BF16) ((ushort*)Cout)[(size_t)row * N + col] = f2bf(v);
                else          ((float*)Cout)[(size_t)row * N + col] = v;
            }
        }
    }
}

__global__ __launch_bounds__(256) void heads_kernel(
    const float* __restrict__ x2,
    const float* __restrict__ wc, const float* __restrict__ bc,
    const float* __restrict__ wb, const float* __restrict__ bb,
    float* __restrict__ out)
{
    int w = threadIdx.x >> 6, l = threadIdx.x & 63;
    int row = blockIdx.x * 4 + w;
    const float* xr = x2 + (size_t)row * 1024;
    float acc[10];
    #pragma unroll
    for (int o = 0; o < 10; ++o) acc[o] = 0.f;
    for (int i = 0; i < 16; ++i) {
        int k = i * 64 + l;
        float xv = xr[k];
        #pragma unroll
        for (int o = 0; o < 2; ++o) acc[o] += xv * wc[o * 1024 + k];
        #pragma unroll
        for (int o = 0; o < 8; ++o) acc[2 + o] += xv * wb[o * 1024 + k];
    }
    #pragma unroll
    for (int o = 0; o < 10; ++o) {
        float v = acc[o];
        #pragma unroll
        for (int s = 32; s > 0; s >>= 1) v += __shfl_xor(v, s, 64);
        acc[o] = v;
    }
    if (l == 0) {
        float* cls = out;
        float* bbx = out + 2048 * 2;
        cls[row * 2 + 0] = acc[0] + bc[0];
        cls[row * 2 + 1] = acc[1] + bc[1];
        #pragma unroll
        for (int o = 0; o < 8; ++o) bbx[row * 8 + o] = acc[2 + o] + bb[o];
    }
}

__global__ __launch_bounds__(256) void decode_kernel(
    const float* __restrict__ props, float* __restrict__ out)
{
    int r = blockIdx.x * 256 + threadIdx.x;
    if (r >= 2048) return;
    const float* cls = out;
    const float* bbx = out + 4096;
    float* boxes  = out + 20480;
    float* scores = out + 36864;
    float px1 = props[r * 4 + 0], py1 = props[r * 4 + 1];
    float px2 = props[r * 4 + 2], py2 = props[r * 4 + 3];
    float pw = px2 - px1, ph = py2 - py1;
    float cx = px1 + 0.5f * pw, cy = py1 + 0.5f * ph;
    const float CLIP = 4.135166556742356f;
    #pragma unroll
    for (int k = 0; k < 2; ++k) {
        float dx = bbx[r * 8 + k * 4 + 0] * 0.1f;
        float dy = bbx[r * 8 + k * 4 + 1] * 0.1f;
        float dw = fminf(bbx[r * 8 + k * 4 + 2] * 0.2f, CLIP);
        float dh = fminf(bbx[r * 8 + k * 4 + 3] * 0.2f, CLIP);
        float pcx = dx * pw + cx, pcy = dy * ph + cy;
        float ppw = expf(dw) * pw, pph = expf(dh) * ph;
        float v0 = pcx - 0.5f * ppw, v1 = pcy - 0.5f * pph;
        float v2 = pcx + 0.5f * ppw, v3 = pcy + 0.5f * pph;
        boxes[r * 8 + k * 4 + 0] = fminf(fmaxf(v0, 0.f), 1024.f);
        boxes[r * 8 + k * 4 + 1] = fminf(fmaxf(v1, 0.f), 1024.f);
        boxes[r * 8 + k * 4 + 2] = fminf(fmaxf(v2, 0.f), 1024.f);
        boxes[r * 8 + k * 4 + 3] = fminf(fmaxf(v3, 0.f), 1024.f);
    }
    float s0 = cls[r * 2], s1 = cls[r * 2 + 1];
    float m = fmaxf(s0, s1);
    float e0 = expf(s0 - m), e1 = expf(s1 - m);
    float inv = 1.f / (e0 + e1);
    scores[r * 2 + 0] = e0 * inv;
    scores[r * 2 + 1] = e1 * inv;
}

// ---------- launch ----------
extern "C" void kernel_launch(void* const* d_in, const int* in_sizes, int n_in,
                              void* d_out, int out_size, void* d_ws, size_t ws_size,
                              hipStream_t stream) {
    const float* feat  = (const float*)d_in[0];
    const float* props = (const float*)d_in[1];
    const float* w1    = (const float*)d_in[2];
    const float* b1    = (const float*)d_in[3];
    const float* w2    = (const float*)d_in[4];
    const float* b2    = (const float*)d_in[5];
    const float* wc    = (const float*)d_in[6];
    const float* bc    = (const float*)d_in[7];
    const float* wb    = (const float*)d_in[8];
    const float* bb    = (const float*)d_in[9];
    float* out = (float*)d_out;

    char* ws = (char*)d_ws;
    ushort* pooled = (ushort*)(ws);                          // 51,380,224 B
    ushort* w1b    = (ushort*)(ws + 51380224);               // 25,690,112 B
    ushort* w2b    = (ushort*)(ws + 51380224 + 25690112);    //  2,097,152 B
    ushort* x1     = (ushort*)(ws + 79167488);               //  4,194,304 B
    float*  x2     = (float*) (ws + 83361792);               //  8,388,608 B (fallback only)
    float*  featT  = (float*) (ws + 83361792);               // aliases x2 (dead by gemm2)
    float*  part   = (float*) (ws + 91750400);               // split-K partials
    const size_t WS_NEED8  = 91750400 + 67108864;            // splitK=8:  67.1 MB
    const size_t WS_NEED4  = 91750400 + 33554432;            // splitK=4:  33.5 MB

    const int M = 2048, N = 1024;
    const int MN = M * N;

    transpose_feat_kernel<<<512, 256, 0, stream>>>(feat, featT);

    if (ws_size >= WS_NEED8) {
        roi_conv_kernel<<<3744, 1024, 0, stream>>>(featT, props, pooled, w1, w1b, w2, w2b);
        gemm_bt_split<<<dim3(N / 128, M / 128, 8), 256, 0, stream>>>(pooled, w1b, part, M, N, 12544, 1568);
        reduce_split_kernel<true ><<<MN / 1024, 256, 0, stream>>>(part, b1, x1, MN, N, 8, 1);
        gemm_bt_split<<<dim3(N / 128, M / 128, 4), 256, 0, stream>>>(x1, w2b, part, M, N, 1024, 256);
        fused_tail_kernel<<<2048, 256, 0, stream>>>(part, b2, wc, bc, wb, bb, props, out, 4);
    } else if (ws_size >= WS_NEED4) {
        roi_conv_kernel<<<3744, 1024, 0, stream>>>(featT, props, pooled, w1, w1b, w2, w2b);
        gemm_bt_split<<<dim3(N / 128, M / 128, 4), 256, 0, stream>>>(pooled, w1b, part, M, N, 12544, 3136);
        reduce_split_kernel<true ><<<MN / 1024, 256, 0, stream>>>(part, b1, x1, MN, N, 4, 1);
        gemm_bt_split<<<dim3(N / 128, M / 128, 4), 256, 0, stream>>>(x1, w2b, part, M, N, 1024, 256);
        fused_tail_kernel<<<2048, 256, 0, stream>>>(part, b2, wc, bc, wb, bb, props, out, 4);
    } else {
        f32_to_bf16_kernel<<<12845056 / 2048, 256, 0, stream>>>(w1, w1b, 12845056);
        f32_to_bf16_kernel<<<1048576 / 2048, 256, 0, stream>>>(w2, w2b, 1048576);
        roi_align_kernel<<<2048, 512, 0, stream>>>(featT, props, pooled);
        gemm_bt<true ><<<dim3(N / 64, M / 128), 256, 0, stream>>>(pooled, w1b, b1, x1, M, N, 12544, 1);
        gemm_bt<false><<<dim3(N / 64, M / 128), 256, 0, stream>>>(x1, w2b, b2, x2, M, N, 1024, 1);
        heads_kernel<<<512, 256, 0, stream>>>(x2, wc, bc, wb, bb, out);
        decode_kernel<<<8, 256, 0, stream>>>(props, out);
    }
}